// Round 1
// baseline (2045.566 us; speedup 1.0000x reference)
//
#include <hip/hip_runtime.h>
#include <cmath>

#define BATCH_ 16
#define SN_ 1024
#define DN_ 1024

constexpr float EPS_ = 1e-3f;

// ---------------- GEMM: C = op(A) * B, all dims 1024, row-major ----------------
// TRANS_A=false: A is [1024 x 1024], C[m,n] = sum_k A[m,k] B[k,n]
// TRANS_A=true : A is [1024 x 1024], C[m,n] = sum_k A[k,m] B[k,n]
// Epilogue: C row r scaled by exp2f(coef * r)   (coef==0 -> no scale)
template<bool TRANS_A>
__global__ __launch_bounds__(256)
void gemm_k(const float* __restrict__ A0, const float* __restrict__ B0,
            float* __restrict__ C0, long sA, long sB, long sC, float coef)
{
    constexpr int K = 1024;
    const int bz = blockIdx.z;
    const float* A  = A0 + (long)bz * sA;
    const float* Bp = B0 + (long)bz * sB;
    float* C = C0 + (long)bz * sC;
    const int m0 = blockIdx.y * 128;
    const int n0 = blockIdx.x * 128;
    const int t  = threadIdx.x;
    const int tx = t & 15, ty = t >> 4;

    __shared__ float As[16][128];
    __shared__ float Bs[16][128];

    float acc[8][8];
#pragma unroll
    for (int i = 0; i < 8; i++)
#pragma unroll
        for (int j = 0; j < 8; j++) acc[i][j] = 0.f;

    for (int k0 = 0; k0 < K; k0 += 16) {
        // ---- load B tile [16][128] (coalesced float4) ----
        {
            int kr = t >> 5, c = (t & 31) * 4;
            float4 v0 = *(const float4*)(Bp + (long)(k0 + kr) * DN_ + n0 + c);
            float4 v1 = *(const float4*)(Bp + (long)(k0 + kr + 8) * DN_ + n0 + c);
            *(float4*)&Bs[kr][c]     = v0;
            *(float4*)&Bs[kr + 8][c] = v1;
        }
        // ---- load A tile ----
        if (TRANS_A) {
            int kr = t >> 5, c = (t & 31) * 4;
            float4 v0 = *(const float4*)(A + (long)(k0 + kr) * DN_ + m0 + c);
            float4 v1 = *(const float4*)(A + (long)(k0 + kr + 8) * DN_ + m0 + c);
            *(float4*)&As[kr][c]     = v0;
            *(float4*)&As[kr + 8][c] = v1;
        } else {
            int r = t >> 2, k4 = (t & 3) * 4;
            float4 v0 = *(const float4*)(A + (long)(m0 + r) * K + k0 + k4);
            float4 v1 = *(const float4*)(A + (long)(m0 + r + 64) * K + k0 + k4);
            As[k4 + 0][r] = v0.x; As[k4 + 1][r] = v0.y;
            As[k4 + 2][r] = v0.z; As[k4 + 3][r] = v0.w;
            As[k4 + 0][r + 64] = v1.x; As[k4 + 1][r + 64] = v1.y;
            As[k4 + 2][r + 64] = v1.z; As[k4 + 3][r + 64] = v1.w;
        }
        __syncthreads();

#pragma unroll
        for (int kk = 0; kk < 16; kk++) {
            float4 a0 = *(const float4*)&As[kk][ty * 4];
            float4 a1 = *(const float4*)&As[kk][ty * 4 + 64];
            float4 b0 = *(const float4*)&Bs[kk][tx * 4];
            float4 b1 = *(const float4*)&Bs[kk][tx * 4 + 64];
            float av[8] = {a0.x, a0.y, a0.z, a0.w, a1.x, a1.y, a1.z, a1.w};
            float bv[8] = {b0.x, b0.y, b0.z, b0.w, b1.x, b1.y, b1.z, b1.w};
#pragma unroll
            for (int i = 0; i < 8; i++)
#pragma unroll
                for (int j = 0; j < 8; j++)
                    acc[i][j] = fmaf(av[i], bv[j], acc[i][j]);
        }
        __syncthreads();
    }

    // ---- epilogue with optional per-row gamma^row scaling ----
#pragma unroll
    for (int ih = 0; ih < 2; ih++)
#pragma unroll
        for (int i = 0; i < 4; i++) {
            int row = m0 + ty * 4 + ih * 64 + i;
            float s = 1.0f;
            if (coef != 0.0f) s = exp2f(coef * (float)row);
#pragma unroll
            for (int jh = 0; jh < 2; jh++) {
                float4 o;
                o.x = acc[ih * 4 + i][jh * 4 + 0] * s;
                o.y = acc[ih * 4 + i][jh * 4 + 1] * s;
                o.z = acc[ih * 4 + i][jh * 4 + 2] * s;
                o.w = acc[ih * 4 + i][jh * 4 + 3] * s;
                *(float4*)&C[(long)row * DN_ + n0 + tx * 4 + jh * 64] = o;
            }
        }
}

// ---------------- GroupNorm over seq axis (groups == channels) ----------------
// stage 1: partial sum / sumsq per (s-chunk, b, d)
__global__ __launch_bounds__(256)
void stats1(const float* __restrict__ y, float* __restrict__ psum,
            float* __restrict__ psumsq)
{
    int d = blockIdx.x * 256 + threadIdx.x;
    int b = blockIdx.y;
    int z = blockIdx.z;
    const float* p = y + ((long)b * SN_ + (long)z * 128) * DN_ + d;
    float s = 0.f, ss = 0.f;
    for (int i = 0; i < 128; i++) {
        float v = p[(long)i * DN_];
        s += v;
        ss += v * v;
    }
    long o = ((long)z * BATCH_ + b) * DN_ + d;
    psum[o] = s;
    psumsq[o] = ss;
}

// stage 2: finalize -> fused scale / bias per (b,d)
__global__ __launch_bounds__(256)
void stats2(const float* __restrict__ psum, const float* __restrict__ psumsq,
            const float* __restrict__ gsc, const float* __restrict__ gbt,
            float* __restrict__ fs, float* __restrict__ bias)
{
    int d = blockIdx.x * 256 + threadIdx.x;
    int b = blockIdx.y;
    float s = 0.f, ss = 0.f;
    for (int z = 0; z < 8; z++) {
        long o = ((long)z * BATCH_ + b) * DN_ + d;
        s += psum[o];
        ss += psumsq[o];
    }
    float mean = s * (1.0f / SN_);
    float var  = ss * (1.0f / SN_) - mean * mean;
    var = fmaxf(var, 0.0f);
    float rstd = rsqrtf(var + EPS_);
    float f = rstd * gsc[d];
    fs[(long)b * DN_ + d]   = f;
    bias[(long)b * DN_ + d] = gbt[d] - mean * f;
}

// stage 3: in-place normalize of y (held in d_out)
__global__ __launch_bounds__(256)
void norm_k(float* __restrict__ y, const float* __restrict__ fs,
            const float* __restrict__ bias)
{
    long i4 = (long)blockIdx.x * 256 + threadIdx.x;
    long e  = i4 * 4;
    int d = (int)(e & (DN_ - 1));
    int b = (int)(e >> 20);  // e / (S*D) = e / 1048576
    float4 v = *(float4*)&y[e];
    long o = (long)b * DN_ + d;
    float4 f  = *(const float4*)&fs[o];
    float4 bb = *(const float4*)&bias[o];
    v.x = v.x * f.x + bb.x;
    v.y = v.y * f.y + bb.y;
    v.z = v.z * f.z + bb.z;
    v.w = v.w * f.w + bb.w;
    *(float4*)&y[e] = v;
}

extern "C" void kernel_launch(void* const* d_in, const int* in_sizes, int n_in,
                              void* d_out, int out_size, void* d_ws, size_t ws_size,
                              hipStream_t stream)
{
    const float* x   = (const float*)d_in[0];
    const float* Wq  = (const float*)d_in[1];
    const float* Wk  = (const float*)d_in[2];
    const float* Wv  = (const float*)d_in[3];
    const float* gsc = (const float*)d_in[4];
    const float* gbt = (const float*)d_in[5];
    float* out = (float*)d_out;

    const long SD = (long)SN_ * DN_;
    const long DD = (long)DN_ * DN_;
    const size_t MB64 = (size_t)SD * BATCH_ * sizeof(float);  // 64 MiB

    char* ws = (char*)d_ws;
    float* KQ = (float*)ws;                // K' buffer, later reused for Q'
    float* V  = (float*)(ws + MB64);
    float* M  = (float*)(ws + 2 * MB64);
    // stats region reuses V's slot (V dead after the M GEMM)
    float* psum   = (float*)(ws + MB64);
    float* psumsq = (float*)(ws + MB64 + (1 << 20));
    float* fs     = (float*)(ws + MB64 + (2 << 20));
    float* bias   = (float*)(ws + MB64 + (2 << 20) + (1 << 18));

    // gamma^r = exp2(r * log2(gamma)); log2(0.96875) computed in double on host
    const float lgf = (float)log2(0.96875);

    dim3 blk(256);
    dim3 grd(8, 8, BATCH_);

    // K' = (x @ Wk) with row j scaled by gamma^{-j}
    gemm_k<false><<<grd, blk, 0, stream>>>(x, Wk, KQ, SD, 0, SD, -lgf);
    // V = x @ Wv
    gemm_k<false><<<grd, blk, 0, stream>>>(x, Wv, V, SD, 0, SD, 0.0f);
    // M = K'^T @ V  (per batch)
    gemm_k<true ><<<grd, blk, 0, stream>>>(KQ, V, M, SD, SD, DD, 0.0f);
    // Q' = (x @ Wq) with row i scaled by gamma^{i}
    gemm_k<false><<<grd, blk, 0, stream>>>(x, Wq, KQ, SD, 0, SD, lgf);
    // y = Q' @ M  -> d_out (per batch)
    gemm_k<false><<<grd, blk, 0, stream>>>(KQ, M, out, SD, DD, SD, 0.0f);

    // GroupNorm over seq per (b, channel)
    stats1<<<dim3(4, 16, 8), blk, 0, stream>>>(out, psum, psumsq);
    stats2<<<dim3(4, 16), blk, 0, stream>>>(psum, psumsq, gsc, gbt, fs, bias);
    norm_k<<<dim3(16384), blk, 0, stream>>>(out, fs, bias);
}

// Round 2
// 354.356 us; speedup vs baseline: 5.7726x; 5.7726x over previous
//
#include <hip/hip_runtime.h>
#include <cmath>

#define BATCH_ 16
#define SN_ 1024
#define DN_ 1024

constexpr float EPS_ = 1e-3f;

typedef unsigned short ushort;
typedef __attribute__((ext_vector_type(8))) short short8;
typedef __attribute__((ext_vector_type(8))) unsigned short ushort8;
typedef __attribute__((ext_vector_type(4))) float f32x4;

__device__ __forceinline__ ushort f2b(float f) {
    unsigned u = __float_as_uint(f);
    unsigned r = (u + 0x7fffu + ((u >> 16) & 1u)) >> 16;
    return (ushort)r;
}

__device__ __forceinline__ void gload16(const void* g, void* l) {
    __builtin_amdgcn_global_load_lds(
        (const __attribute__((address_space(1))) void*)g,
        (__attribute__((address_space(3))) void*)l, 16, 0, 0);
}

// ---------------------------------------------------------------------------
// bf16 MFMA GEMM, m97 structure: 128x128 tile, BK=32, 256 thr (4 waves),
// A row-major [M][K], B in B^T layout [N][K]. All dims 1024.
// MODE 0: fp32 out plain        (y = Q' Mt)
// MODE 1: bf16 out, row-scale   (Q')
// MODE 2: bf16 out, transposed  (V't)
// MODE 3: bf16 out, transposed + row-scale (K't)
// MODE 4: bf16 out plain        (Mt)
// row-scale: acc row r *= exp2(coef * global_row)
// ---------------------------------------------------------------------------
template<int MODE>
__global__ __launch_bounds__(256)
void gemm_bf(const ushort* __restrict__ A0, const ushort* __restrict__ B0,
             void* __restrict__ C0, long sA, long sB, long sC, float coef)
{
    constexpr bool TRANSP = (MODE == 2 || MODE == 3);
    constexpr bool SCALE  = (MODE == 1 || MODE == 3);
    constexpr int  LDSB   = TRANSP ? (128 * 130 * 2) : 16384;
    __shared__ __align__(16) char lds_raw[LDSB];
    ushort (*Als)[32] = (ushort(*)[32])lds_raw;
    ushort (*Bls)[32] = (ushort(*)[32])(lds_raw + 8192);

    const int t  = threadIdx.x;
    const int bz = blockIdx.z;
    const ushort* A = A0 + (long)bz * sA;
    const ushort* B = B0 + (long)bz * sB;
    const int m0 = blockIdx.y * 128, n0 = blockIdx.x * 128;
    const int l  = t & 63, w = t >> 6;
    const int wr = (w >> 1) * 64, wc = (w & 1) * 64;
    const int lr = l & 15;
    const int kh = l >> 4;

    f32x4 acc[4][4] = {};

    // staging coords: thread t -> LDS byte offset t*16 (linear per wave)
    const int ar = t >> 2, ac = (t & 3) * 8;
    const ushort* ga0 = A + (long)(m0 + ar) * 1024 + ac;
    const ushort* ga1 = A + (long)(m0 + 64 + ar) * 1024 + ac;
    const ushort* gb0 = B + (long)(n0 + ar) * 1024 + ac;
    const ushort* gb1 = B + (long)(n0 + 64 + ar) * 1024 + ac;
    void* la0 = &Als[ar][ac];
    void* la1 = &Als[64 + ar][ac];
    void* lb0 = &Bls[ar][ac];
    void* lb1 = &Bls[64 + ar][ac];

    for (int k0 = 0; k0 < 1024; k0 += 32) {
        gload16(ga0 + k0, la0);
        gload16(ga1 + k0, la1);
        gload16(gb0 + k0, lb0);
        gload16(gb1 + k0, lb1);
        __syncthreads();

        short8 af[4], bfr[4];
#pragma unroll
        for (int i = 0; i < 4; i++) {
            af[i]  = *(const short8*)&Als[wr + i * 16 + lr][kh * 8];
            bfr[i] = *(const short8*)&Bls[wc + i * 16 + lr][kh * 8];
        }
#pragma unroll
        for (int i = 0; i < 4; i++)
#pragma unroll
            for (int j = 0; j < 4; j++)
                acc[i][j] = __builtin_amdgcn_mfma_f32_16x16x32_bf16(
                    af[i], bfr[j], acc[i][j], 0, 0, 0);
        __syncthreads();
    }

    // ---- epilogue ----
    if constexpr (MODE == 0) {
        float* C = (float*)C0 + (long)bz * sC;
#pragma unroll
        for (int i = 0; i < 4; i++)
#pragma unroll
            for (int reg = 0; reg < 4; reg++) {
                int row = m0 + wr + i * 16 + kh * 4 + reg;
#pragma unroll
                for (int j = 0; j < 4; j++)
                    C[(long)row * 1024 + n0 + wc + j * 16 + lr] = acc[i][j][reg];
            }
    } else if constexpr (!TRANSP) {
        ushort* C = (ushort*)C0 + (long)bz * sC;
#pragma unroll
        for (int i = 0; i < 4; i++)
#pragma unroll
            for (int reg = 0; reg < 4; reg++) {
                int row = m0 + wr + i * 16 + kh * 4 + reg;
                float s = SCALE ? exp2f(coef * (float)row) : 1.0f;
#pragma unroll
                for (int j = 0; j < 4; j++)
                    C[(long)row * 1024 + n0 + wc + j * 16 + lr] =
                        f2b(acc[i][j][reg] * s);
            }
    } else {
        // transposed store via LDS bounce: C^T[n][m], coalesced rows of m
        ushort (*T)[130] = (ushort(*)[130])lds_raw;
#pragma unroll
        for (int i = 0; i < 4; i++)
#pragma unroll
            for (int reg = 0; reg < 4; reg++) {
                int r = wr + i * 16 + kh * 4 + reg;  // local row (s-dim)
                float s = SCALE ? exp2f(coef * (float)(m0 + r)) : 1.0f;
#pragma unroll
                for (int j = 0; j < 4; j++)
                    T[r][wc + j * 16 + lr] = f2b(acc[i][j][reg] * s);
            }
        __syncthreads();
        ushort* Ct = (ushort*)C0 + (long)bz * sC;
#pragma unroll
        for (int rep = 0; rep < 8; rep++) {
            int d  = rep * 16 + (t >> 4);
            int s0 = (t & 15) * 8;
            ushort8 v;
#pragma unroll
            for (int j = 0; j < 8; j++) v[j] = T[s0 + j][d];
            *(ushort8*)&Ct[(long)(n0 + d) * 1024 + m0 + s0] = v;
        }
    }
}

// ---------------- prepass: fp32 -> bf16 convert ----------------
__global__ __launch_bounds__(256)
void conv_x_k(const float* __restrict__ x, ushort* __restrict__ xb)
{
    long i = ((long)blockIdx.x * 256 + threadIdx.x) * 8;
    float4 a = *(const float4*)&x[i];
    float4 b = *(const float4*)&x[i + 4];
    ushort8 v;
    v[0] = f2b(a.x); v[1] = f2b(a.y); v[2] = f2b(a.z); v[3] = f2b(a.w);
    v[4] = f2b(b.x); v[5] = f2b(b.y); v[6] = f2b(b.z); v[7] = f2b(b.w);
    *(ushort8*)&xb[i] = v;
}

// ---------------- prepass: weight transpose + convert ----------------
__global__ __launch_bounds__(256)
void wt_k(const float* __restrict__ W, ushort* __restrict__ Wt)
{
    __shared__ float Tl[32][33];
    int tx = threadIdx.x & 31, ty = threadIdx.x >> 5;
    int c0 = blockIdx.x * 32, r0 = blockIdx.y * 32;
#pragma unroll
    for (int i = 0; i < 4; i++)
        Tl[ty + 8 * i][tx] = W[(long)(r0 + ty + 8 * i) * 1024 + c0 + tx];
    __syncthreads();
#pragma unroll
    for (int i = 0; i < 4; i++)
        Wt[(long)(c0 + ty + 8 * i) * 1024 + r0 + tx] = f2b(Tl[tx][ty + 8 * i]);
}

// ---------------- GroupNorm over seq axis ----------------
__global__ __launch_bounds__(256)
void stats1(const float* __restrict__ y, float* __restrict__ psum,
            float* __restrict__ psumsq)
{
    int d = blockIdx.x * 256 + threadIdx.x;
    int b = blockIdx.y;
    int z = blockIdx.z;
    const float* p = y + ((long)b * SN_ + (long)z * 128) * DN_ + d;
    float s = 0.f, ss = 0.f;
    for (int i = 0; i < 128; i++) {
        float v = p[(long)i * DN_];
        s += v;
        ss += v * v;
    }
    long o = ((long)z * BATCH_ + b) * DN_ + d;
    psum[o] = s;
    psumsq[o] = ss;
}

__global__ __launch_bounds__(256)
void stats2(const float* __restrict__ psum, const float* __restrict__ psumsq,
            const float* __restrict__ gsc, const float* __restrict__ gbt,
            float* __restrict__ fs, float* __restrict__ bias)
{
    int d = blockIdx.x * 256 + threadIdx.x;
    int b = blockIdx.y;
    float s = 0.f, ss = 0.f;
    for (int z = 0; z < 8; z++) {
        long o = ((long)z * BATCH_ + b) * DN_ + d;
        s += psum[o];
        ss += psumsq[o];
    }
    float mean = s * (1.0f / SN_);
    float var  = ss * (1.0f / SN_) - mean * mean;
    var = fmaxf(var, 0.0f);
    float rstd = rsqrtf(var + EPS_);
    float f = rstd * gsc[d];
    fs[(long)b * DN_ + d]   = f;
    bias[(long)b * DN_ + d] = gbt[d] - mean * f;
}

__global__ __launch_bounds__(256)
void norm_k(float* __restrict__ y, const float* __restrict__ fs,
            const float* __restrict__ bias)
{
    long i4 = (long)blockIdx.x * 256 + threadIdx.x;
    long e  = i4 * 4;
    int d = (int)(e & (DN_ - 1));
    int b = (int)(e >> 20);
    float4 v = *(float4*)&y[e];
    long o = (long)b * DN_ + d;
    float4 f  = *(const float4*)&fs[o];
    float4 bb = *(const float4*)&bias[o];
    v.x = v.x * f.x + bb.x;
    v.y = v.y * f.y + bb.y;
    v.z = v.z * f.z + bb.z;
    v.w = v.w * f.w + bb.w;
    *(float4*)&y[e] = v;
}

extern "C" void kernel_launch(void* const* d_in, const int* in_sizes, int n_in,
                              void* d_out, int out_size, void* d_ws, size_t ws_size,
                              hipStream_t stream)
{
    const float* x   = (const float*)d_in[0];
    const float* Wq  = (const float*)d_in[1];
    const float* Wk  = (const float*)d_in[2];
    const float* Wv  = (const float*)d_in[3];
    const float* gsc = (const float*)d_in[4];
    const float* gbt = (const float*)d_in[5];
    float* out = (float*)d_out;

    const long SD = (long)SN_ * DN_;            // 1 Mi elems
    const long DD = (long)DN_ * DN_;
    const size_t MB32 = (size_t)SD * BATCH_ * sizeof(ushort);  // 32 MiB

    char* ws = (char*)d_ws;
    ushort* xb  = (ushort*)(ws);
    ushort* Qp  = (ushort*)(ws + 1 * MB32);
    ushort* Kt  = (ushort*)(ws + 2 * MB32);
    ushort* Vt  = (ushort*)(ws + 3 * MB32);
    ushort* Mt  = (ushort*)(ws + 4 * MB32);
    ushort* Wtq = (ushort*)(ws + 5 * MB32);
    ushort* Wtk = (ushort*)(ws + 5 * MB32 + (2u << 20));
    ushort* Wtv = (ushort*)(ws + 5 * MB32 + (4u << 20));
    float*  psum   = (float*)(ws + 5 * MB32 + (6u << 20));
    float*  psumsq = (float*)(ws + 5 * MB32 + (6u << 20) + (1u << 19));
    float*  fs     = (float*)(ws + 5 * MB32 + (7u << 20));
    float*  bias   = (float*)(ws + 5 * MB32 + (7u << 20) + (1u << 18));

    const float lgf = (float)log2(0.96875);  // log2(gamma)

    dim3 blk(256);
    dim3 grd(8, 8, BATCH_);

    // prepass
    conv_x_k<<<dim3(8192), blk, 0, stream>>>(x, xb);
    wt_k<<<dim3(32, 32), blk, 0, stream>>>(Wq, Wtq);
    wt_k<<<dim3(32, 32), blk, 0, stream>>>(Wk, Wtk);
    wt_k<<<dim3(32, 32), blk, 0, stream>>>(Wv, Wtv);

    // Q' = (x Wq) * gamma^s        [B][S][D] bf16
    gemm_bf<1><<<grd, blk, 0, stream>>>(xb, Wtq, Qp, SD, 0, SD, lgf);
    // K't = ((x Wk) * gamma^-s)^T  [B][D][S] bf16
    gemm_bf<3><<<grd, blk, 0, stream>>>(xb, Wtk, Kt, SD, 0, SD, -lgf);
    // V't = (x Wv)^T               [B][D][S] bf16
    gemm_bf<2><<<grd, blk, 0, stream>>>(xb, Wtv, Vt, SD, 0, SD, 0.0f);
    // Mt = V't · K't^T(B^T-layout) = (K'^T V)^T   [B][D][D] bf16
    gemm_bf<4><<<grd, blk, 0, stream>>>(Vt, Kt, Mt, SD, SD, DD, 0.0f);
    // y = Q' · Mt^T(B^T-layout) = Q' M   [B][S][D] fp32 -> d_out
    gemm_bf<0><<<grd, blk, 0, stream>>>(Qp, Mt, out, SD, DD, SD, 0.0f);

    // GroupNorm over seq per (b, channel)
    stats1<<<dim3(4, 16, 8), blk, 0, stream>>>(out, psum, psumsq);
    stats2<<<dim3(4, 16), blk, 0, stream>>>(psum, psumsq, gsc, gbt, fs, bias);
    norm_k<<<dim3(16384), blk, 0, stream>>>(out, fs, bias);
}

// Round 3
// 304.657 us; speedup vs baseline: 6.7143x; 1.1631x over previous
//
#include <hip/hip_runtime.h>
#include <cmath>

#define BATCH_ 16
#define SN_ 1024
#define DN_ 1024

constexpr float EPS_ = 1e-3f;

typedef unsigned short ushort;
typedef __attribute__((ext_vector_type(8))) short short8;
typedef __attribute__((ext_vector_type(8))) unsigned short ushort8;
typedef __attribute__((ext_vector_type(4))) float f32x4;

__device__ __forceinline__ ushort f2b(float f) {
    unsigned u = __float_as_uint(f);
    unsigned r = (u + 0x7fffu + ((u >> 16) & 1u)) >> 16;
    return (ushort)r;
}

__device__ __forceinline__ void gload16(const void* g, void* l) {
    __builtin_amdgcn_global_load_lds(
        (const __attribute__((address_space(1))) void*)g,
        (__attribute__((address_space(3))) void*)l, 16, 0, 0);
}

// ---------------------------------------------------------------------------
// bf16 MFMA GEMM, 256x256 tile, BK=64, 512 thr (8 waves, 2Mx4N), double-buffered
// 128 KiB LDS with (row&7) 16B-slot XOR swizzle. A row-major [M][K], B in B^T
// layout [N][K], K = 1024.
// MODE 0: fp32 out plain              (y = Q' Mt)
// MODE 1: bf16 out, row-scale         (Q')
// MODE 2: bf16 out, transposed        (V't)
// MODE 3: bf16 out, transposed+scale  (K't)
// MODE 4: bf16 out plain              (Mt)
// row-scale uses (global_row & 1023) = s within batch.
// B pointer: B0 + bz*sB + (m0>>10)*sBm  (sBm: per-batch B for the y-GEMM)
// ---------------------------------------------------------------------------
template<int MODE>
__global__ __launch_bounds__(512, 2)
void gemm_bf(const ushort* __restrict__ A0, const ushort* __restrict__ B0,
             void* __restrict__ C0, long sA, long sB, long sBm, long sC,
             float coef)
{
    constexpr bool TRANSP = (MODE == 2 || MODE == 3);
    constexpr bool SCALE  = (MODE == 1 || MODE == 3);

    __shared__ __align__(16) char lds[131072];  // 2 bufs x (A 32K + B 32K)

    // ---- bijective XCD swizzle (total blocks == 256, % 8 == 0) ----
    const int gx = gridDim.x, gy = gridDim.y;
    int lid   = blockIdx.x + gx * (blockIdx.y + gy * blockIdx.z);
    int total = gx * gy * gridDim.z;
    int swz   = (lid & 7) * (total >> 3) + (lid >> 3);
    int bx = swz % gx;
    int rest = swz / gx;
    int by = rest % gy;
    int bz = rest / gy;

    const int m0 = by * 256, n0 = bx * 256;
    const ushort* A  = A0 + (long)bz * sA;
    const ushort* Bp = B0 + (long)bz * sB + (long)(m0 >> 10) * sBm;

    const int t = threadIdx.x;
    const int l = t & 63, w = t >> 6;
    const int wr = w >> 2, wc = w & 3;    // wave grid 2M x 4N
    const int lr = l & 15, kh = l >> 4;   // fragment lane coords

    // ---- staging coords: thread t covers 16B; 8 loads/tile (4 A + 4 B) ----
    // LDS dest linear (required); global source pre-swizzled so that the
    // swizzled *read* below sees the right data (both-sides rule).
    const int rl   = t >> 3;                       // 0..63 row-in-chunk
    const int slot = (t & 7) ^ (rl & 7);           // inverse == forward (XOR)
    const ushort* gA = A  + (long)(m0 + rl) * 1024 + slot * 8;
    const ushort* gB = Bp + (long)(n0 + rl) * 1024 + slot * 8;
    char* lA = lds + t * 16;            // + buf*65536 + chunk*8192
    char* lB = lds + 32768 + t * 16;

    // ---- fragment read offsets (swizzled): byte = row*128 + slot'*16 ----
    const int rA  = (wr * 128 + lr) * 128;
    const int rB  = (wc * 64 + lr) * 128 + 32768;
    const int sk0 = ((0 + kh) ^ (lr & 7)) * 16;    // k-slice 0
    const int sk1 = ((4 + kh) ^ (lr & 7)) * 16;    // k-slice 1

    f32x4 acc[8][4] = {};

    // prologue: stage tile 0 into buf 0
#pragma unroll
    for (int h = 0; h < 4; ++h) {
        gload16(gA + (long)h * 64 * 1024, lA + h * 8192);
        gload16(gB + (long)h * 64 * 1024, lB + h * 8192);
    }
    __syncthreads();

    int buf = 0;
    for (int kt = 0; kt < 16; ++kt) {
        // stage next tile into buf^1 (full tile of MFMA hides the latency)
        if (kt < 15) {
            int k0 = (kt + 1) * 64;
            int bo = (buf ^ 1) * 65536;
#pragma unroll
            for (int h = 0; h < 4; ++h) {
                gload16(gA + (long)h * 64 * 1024 + k0, lA + bo + h * 8192);
                gload16(gB + (long)h * 64 * 1024 + k0, lB + bo + h * 8192);
            }
        }
        const int bo = buf * 65536;
        // 4 quadrant sub-phases: (mq,nq) of the wave's 8x4 fragment grid
#pragma unroll
        for (int q = 0; q < 4; ++q) {
            const int mq = q & 1, nq = q >> 1;
            short8 af[4][2], bv[2][2];
#pragma unroll
            for (int i = 0; i < 4; ++i) {
                const int mi = mq * 4 + i;
                af[i][0] = *(const short8*)(lds + bo + rA + mi * 2048 + sk0);
                af[i][1] = *(const short8*)(lds + bo + rA + mi * 2048 + sk1);
            }
#pragma unroll
            for (int j = 0; j < 2; ++j) {
                const int nj = nq * 2 + j;
                bv[j][0] = *(const short8*)(lds + bo + rB + nj * 2048 + sk0);
                bv[j][1] = *(const short8*)(lds + bo + rB + nj * 2048 + sk1);
            }
            __builtin_amdgcn_s_setprio(1);
#pragma unroll
            for (int i = 0; i < 4; ++i)
#pragma unroll
                for (int j = 0; j < 2; ++j) {
                    const int mi = mq * 4 + i, nj = nq * 2 + j;
                    acc[mi][nj] = __builtin_amdgcn_mfma_f32_16x16x32_bf16(
                        af[i][0], bv[j][0], acc[mi][nj], 0, 0, 0);
                    acc[mi][nj] = __builtin_amdgcn_mfma_f32_16x16x32_bf16(
                        af[i][1], bv[j][1], acc[mi][nj], 0, 0, 0);
                }
            __builtin_amdgcn_s_setprio(0);
            __builtin_amdgcn_sched_barrier(0);
        }
        __syncthreads();   // drains vmcnt(0): next buf staged AND buf free
        buf ^= 1;
    }

    // ---------------- epilogues ----------------
    if constexpr (MODE == 0) {
        float* C = (float*)C0 + (long)bz * sC;
#pragma unroll
        for (int mi = 0; mi < 8; ++mi)
#pragma unroll
            for (int reg = 0; reg < 4; ++reg) {
                int row = m0 + wr * 128 + mi * 16 + kh * 4 + reg;
#pragma unroll
                for (int nj = 0; nj < 4; ++nj)
                    C[(long)row * 1024 + n0 + wc * 64 + nj * 16 + lr] =
                        acc[mi][nj][reg];
            }
    } else if constexpr (!TRANSP) {
        ushort* C = (ushort*)C0 + (long)bz * sC;
#pragma unroll
        for (int mi = 0; mi < 8; ++mi)
#pragma unroll
            for (int reg = 0; reg < 4; ++reg) {
                int row = m0 + wr * 128 + mi * 16 + kh * 4 + reg;
                float s = SCALE ? exp2f(coef * (float)(row & 1023)) : 1.0f;
#pragma unroll
                for (int nj = 0; nj < 4; ++nj)
                    C[(long)row * 1024 + n0 + wc * 64 + nj * 16 + lr] =
                        f2b(acc[mi][nj][reg] * s);
            }
    } else {
        // transposed store via 2-pass LDS bounce: out[b][d][s]
        ushort (*T)[136] = (ushort(*)[136])lds;
        const int bb = m0 >> 10;          // batch index
        const int ms = m0 & 1023;         // s-offset within batch
        ushort* Ct = (ushort*)C0 + (long)bb * sC;
#pragma unroll
        for (int pass = 0; pass < 2; ++pass) {
            if ((wc >> 1) == pass) {
#pragma unroll
                for (int mi = 0; mi < 8; ++mi)
#pragma unroll
                    for (int reg = 0; reg < 4; ++reg) {
                        int r = wr * 128 + mi * 16 + kh * 4 + reg;
                        float s = SCALE ? exp2f(coef * (float)(ms + r)) : 1.0f;
#pragma unroll
                        for (int nj = 0; nj < 4; ++nj)
                            T[r][(wc & 1) * 64 + nj * 16 + lr] =
                                f2b(acc[mi][nj][reg] * s);
                    }
            }
            __syncthreads();
#pragma unroll
            for (int r2 = 0; r2 < 8; ++r2) {
                int d_loc = r2 * 16 + (t >> 5);
                int s0 = (t & 31) * 8;
                ushort8 v;
#pragma unroll
                for (int jj = 0; jj < 8; ++jj) v[jj] = T[s0 + jj][d_loc];
                *(ushort8*)&Ct[(long)(n0 + pass * 128 + d_loc) * 1024 + ms + s0] = v;
            }
            __syncthreads();
        }
    }
}

// ---------------- prepass: fp32 -> bf16 convert ----------------
__global__ __launch_bounds__(256)
void conv_x_k(const float* __restrict__ x, ushort* __restrict__ xb)
{
    long i = ((long)blockIdx.x * 256 + threadIdx.x) * 8;
    float4 a = *(const float4*)&x[i];
    float4 b = *(const float4*)&x[i + 4];
    ushort8 v;
    v[0] = f2b(a.x); v[1] = f2b(a.y); v[2] = f2b(a.z); v[3] = f2b(a.w);
    v[4] = f2b(b.x); v[5] = f2b(b.y); v[6] = f2b(b.z); v[7] = f2b(b.w);
    *(ushort8*)&xb[i] = v;
}

// ---------------- prepass: weight transpose + convert ----------------
__global__ __launch_bounds__(256)
void wt_k(const float* __restrict__ W, ushort* __restrict__ Wt)
{
    __shared__ float Tl[32][33];
    int tx = threadIdx.x & 31, ty = threadIdx.x >> 5;
    int c0 = blockIdx.x * 32, r0 = blockIdx.y * 32;
#pragma unroll
    for (int i = 0; i < 4; i++)
        Tl[ty + 8 * i][tx] = W[(long)(r0 + ty + 8 * i) * 1024 + c0 + tx];
    __syncthreads();
#pragma unroll
    for (int i = 0; i < 4; i++)
        Wt[(long)(c0 + ty + 8 * i) * 1024 + r0 + tx] = f2b(Tl[tx][ty + 8 * i]);
}

// ---------------- GroupNorm over seq axis ----------------
__global__ __launch_bounds__(256)
void stats1(const float* __restrict__ y, float* __restrict__ psum,
            float* __restrict__ psumsq)
{
    int d = blockIdx.x * 256 + threadIdx.x;
    int b = blockIdx.y;
    int z = blockIdx.z;
    const float* p = y + ((long)b * SN_ + (long)z * 128) * DN_ + d;
    float s = 0.f, ss = 0.f;
    for (int i = 0; i < 128; i++) {
        float v = p[(long)i * DN_];
        s += v;
        ss += v * v;
    }
    long o = ((long)z * BATCH_ + b) * DN_ + d;
    psum[o] = s;
    psumsq[o] = ss;
}

__global__ __launch_bounds__(256)
void stats2(const float* __restrict__ psum, const float* __restrict__ psumsq,
            const float* __restrict__ gsc, const float* __restrict__ gbt,
            float* __restrict__ fs, float* __restrict__ bias)
{
    int d = blockIdx.x * 256 + threadIdx.x;
    int b = blockIdx.y;
    float s = 0.f, ss = 0.f;
    for (int z = 0; z < 8; z++) {
        long o = ((long)z * BATCH_ + b) * DN_ + d;
        s += psum[o];
        ss += psumsq[o];
    }
    float mean = s * (1.0f / SN_);
    float var  = ss * (1.0f / SN_) - mean * mean;
    var = fmaxf(var, 0.0f);
    float rstd = rsqrtf(var + EPS_);
    float f = rstd * gsc[d];
    fs[(long)b * DN_ + d]   = f;
    bias[(long)b * DN_ + d] = gbt[d] - mean * f;
}

__global__ __launch_bounds__(256)
void norm_k(float* __restrict__ y, const float* __restrict__ fs,
            const float* __restrict__ bias)
{
    long i4 = (long)blockIdx.x * 256 + threadIdx.x;
    long e  = i4 * 4;
    int d = (int)(e & (DN_ - 1));
    int b = (int)(e >> 20);
    float4 v = *(float4*)&y[e];
    long o = (long)b * DN_ + d;
    float4 f  = *(const float4*)&fs[o];
    float4 bb = *(const float4*)&bias[o];
    v.x = v.x * f.x + bb.x;
    v.y = v.y * f.y + bb.y;
    v.z = v.z * f.z + bb.z;
    v.w = v.w * f.w + bb.w;
    *(float4*)&y[e] = v;
}

extern "C" void kernel_launch(void* const* d_in, const int* in_sizes, int n_in,
                              void* d_out, int out_size, void* d_ws, size_t ws_size,
                              hipStream_t stream)
{
    const float* x   = (const float*)d_in[0];
    const float* Wq  = (const float*)d_in[1];
    const float* Wk  = (const float*)d_in[2];
    const float* Wv  = (const float*)d_in[3];
    const float* gsc = (const float*)d_in[4];
    const float* gbt = (const float*)d_in[5];
    float* out = (float*)d_out;

    const long SD = (long)SN_ * DN_;
    const long DD = (long)DN_ * DN_;
    const size_t MB32 = (size_t)SD * BATCH_ * sizeof(ushort);  // 32 MiB

    char* ws = (char*)d_ws;
    ushort* xb  = (ushort*)(ws);
    ushort* Qp  = (ushort*)(ws + 1 * MB32);
    ushort* Kt  = (ushort*)(ws + 2 * MB32);
    ushort* Vt  = (ushort*)(ws + 3 * MB32);
    ushort* Mt  = (ushort*)(ws + 4 * MB32);
    ushort* Wtq = (ushort*)(ws + 5 * MB32);
    ushort* Wtk = (ushort*)(ws + 5 * MB32 + (2u << 20));
    ushort* Wtv = (ushort*)(ws + 5 * MB32 + (4u << 20));
    float*  psum   = (float*)(ws + 5 * MB32 + (6u << 20));
    float*  psumsq = (float*)(ws + 5 * MB32 + (6u << 20) + (1u << 19));
    float*  fs     = (float*)(ws + 5 * MB32 + (7u << 20));
    float*  bias   = (float*)(ws + 5 * MB32 + (7u << 20) + (1u << 18));

    const float lgf = (float)log2(0.96875);  // log2(gamma)

    dim3 blk512(512);
    dim3 blk(256);
    dim3 gproj(4, 64);      // N=1024/256, M=16384/256 (batch folded into M)
    dim3 gmt(4, 4, 16);     // per-batch 1024x1024
    dim3 gy(4, 64);

    // prepass
    conv_x_k<<<dim3(8192), blk, 0, stream>>>(x, xb);
    wt_k<<<dim3(32, 32), blk, 0, stream>>>(Wq, Wtq);
    wt_k<<<dim3(32, 32), blk, 0, stream>>>(Wk, Wtk);
    wt_k<<<dim3(32, 32), blk, 0, stream>>>(Wv, Wtv);

    // Q' = (x Wq) * gamma^s            [B*S][D] bf16
    gemm_bf<1><<<gproj, blk512, 0, stream>>>(xb, Wtq, Qp, 0, 0, 0, 0, lgf);
    // K't = ((x Wk) * gamma^-s)^T      [B][D][S] bf16
    gemm_bf<3><<<gproj, blk512, 0, stream>>>(xb, Wtk, Kt, 0, 0, 0, SD, -lgf);
    // V't = (x Wv)^T                   [B][D][S] bf16
    gemm_bf<2><<<gproj, blk512, 0, stream>>>(xb, Wtv, Vt, 0, 0, 0, SD, 0.0f);
    // Mt = V't x Kt(B^T) = M^T         [B][D][D] bf16
    gemm_bf<4><<<gmt, blk512, 0, stream>>>(Vt, Kt, Mt, SD, SD, 0, DD, 0.0f);
    // y = Q' x Mt(B^T, per-batch) = Q' M   [B*S][D] fp32 -> d_out
    gemm_bf<0><<<gy, blk512, 0, stream>>>(Qp, Mt, out, 0, 0, DD, 0, 0.0f);

    // GroupNorm over seq per (b, channel)
    stats1<<<dim3(4, 16, 8), blk, 0, stream>>>(out, psum, psumsq);
    stats2<<<dim3(4, 16), blk, 0, stream>>>(psum, psumsq, gsc, gbt, fs, bias);
    norm_k<<<dim3(16384), blk, 0, stream>>>(out, fs, bias);
}

// Round 4
// 263.501 us; speedup vs baseline: 7.7630x; 1.1562x over previous
//
#include <hip/hip_runtime.h>
#include <cmath>

#define BATCH_ 16
#define SN_ 1024
#define DN_ 1024

constexpr float EPS_ = 1e-3f;

typedef unsigned short ushort;
typedef __attribute__((ext_vector_type(8))) short short8;
typedef __attribute__((ext_vector_type(8))) unsigned short ushort8;
typedef __attribute__((ext_vector_type(16))) float f32x16;

__device__ __forceinline__ ushort f2b(float f) {
    unsigned u = __float_as_uint(f);
    unsigned r = (u + 0x7fffu + ((u >> 16) & 1u)) >> 16;
    return (ushort)r;
}

__device__ __forceinline__ void gload16(const void* g, void* l) {
    __builtin_amdgcn_global_load_lds(
        (const __attribute__((address_space(1))) void*)g,
        (__attribute__((address_space(3))) void*)l, 16, 0, 0);
}

// ---------------------------------------------------------------------------
// bf16 MFMA GEMM, 256x256 tile, BK=64, 512 thr (8 waves, 2Mx4N),
// v_mfma_f32_32x32x16_bf16, read-once fragments, double-buffered 128 KiB LDS.
// LDS tile layout: [256 rows][64 k] bf16 (128 B rows, 8x 16B chunks); chunk c
// of row r stored at physical slot (c ^ (r&7))  -> conflict-free frag reads.
// A row-major [M][K], B in B^T layout [N][K], K = 1024.
// MODE 0: fp32 out plain              (y = Q' Mt)
// MODE 1: bf16 out, row-scale         (Q')
// MODE 2: bf16 out, transposed        (V't)
// MODE 3: bf16 out, transposed+scale  (K't)
// MODE 4: bf16 out plain              (Mt)
// ---------------------------------------------------------------------------
template<int MODE>
__global__ __launch_bounds__(512, 2)
void gemm_bf(const ushort* __restrict__ A0, const ushort* __restrict__ B0,
             void* __restrict__ C0, long sA, long sB, long sBm, long sC,
             float coef)
{
    constexpr bool TRANSP = (MODE == 2 || MODE == 3);
    constexpr bool SCALE  = (MODE == 1 || MODE == 3);

    __shared__ __align__(16) char lds[131072];  // 2 bufs x (A 32K + B 32K)

    // ---- bijective XCD swizzle (total blocks == 256, % 8 == 0) ----
    const int gx = gridDim.x, gy = gridDim.y;
    int lid   = blockIdx.x + gx * (blockIdx.y + gy * blockIdx.z);
    int total = gx * gy * gridDim.z;
    int swz   = (lid & 7) * (total >> 3) + (lid >> 3);
    int bx = swz % gx;
    int rest = swz / gx;
    int by = rest % gy;
    int bz = rest / gy;

    const int m0 = by * 256, n0 = bx * 256;
    const ushort* A  = A0 + (long)bz * sA;
    const ushort* Bp = B0 + (long)bz * sB + (long)(m0 >> 10) * sBm;

    const int t = threadIdx.x;
    const int l = t & 63, w = t >> 6;
    const int wr = w >> 2, wc = w & 3;    // wave grid 2M x 4N
    const int ln = l & 31;                // MFMA row/col lane
    const int kb = l >> 5;                // k half (0/1)
    const int lx = l & 7;                 // swizzle xor for frag reads

    // frag-read lane bases (byte offsets inside a buffer)
    const int aOff = (wr * 128 + ln) * 128;
    const int bOff = 32768 + (wc * 64 + ln) * 128;

    // ---- staging: thread t writes 16B at linear LDS t*16; source address
    //      pre-swizzled so phys slot s of row r holds chunk (s ^ (r&7)).
    const int rl   = t >> 3;                 // row within 64-row chunk
    const int slot = (t & 7) ^ (rl & 7);
    const ushort* gA = A  + (long)(m0 + rl) * 1024 + slot * 8;
    const ushort* gB = Bp + (long)(n0 + rl) * 1024 + slot * 8;
    char* lA = lds + t * 16;                 // + buf*65536 + h*8192
    char* lB = lds + 32768 + t * 16;

    f32x16 acc[4][2] = {};

    // prologue: stage tile 0 into buf 0
#pragma unroll
    for (int h = 0; h < 4; ++h) {
        gload16(gA + (long)h * 64 * 1024, lA + h * 8192);
        gload16(gB + (long)h * 64 * 1024, lB + h * 8192);
    }
    __syncthreads();

    int buf = 0;
    for (int kt = 0; kt < 16; ++kt) {
        if (kt < 15) {
            int k0 = (kt + 1) * 64;
            int bo = (buf ^ 1) * 65536;
#pragma unroll
            for (int h = 0; h < 4; ++h) {
                gload16(gA + (long)h * 64 * 1024 + k0, lA + bo + h * 8192);
                gload16(gB + (long)h * 64 * 1024 + k0, lB + bo + h * 8192);
            }
        }
        const int bo = buf * 65536;
#pragma unroll
        for (int ks = 0; ks < 4; ++ks) {
            const int sx = ((ks * 2 + kb) ^ lx) * 16;
            short8 av[4], bv[2];
#pragma unroll
            for (int mi = 0; mi < 4; ++mi)
                av[mi] = *(const short8*)(lds + bo + aOff + mi * 4096 + sx);
#pragma unroll
            for (int nj = 0; nj < 2; ++nj)
                bv[nj] = *(const short8*)(lds + bo + bOff + nj * 4096 + sx);
            __builtin_amdgcn_s_setprio(1);
#pragma unroll
            for (int mi = 0; mi < 4; ++mi)
#pragma unroll
                for (int nj = 0; nj < 2; ++nj)
                    acc[mi][nj] = __builtin_amdgcn_mfma_f32_32x32x16_bf16(
                        av[mi], bv[nj], acc[mi][nj], 0, 0, 0);
            __builtin_amdgcn_s_setprio(0);
        }
        __syncthreads();   // drains vmcnt(0): next buf staged AND buf free
        buf ^= 1;
    }

    // C/D 32x32 layout: col = ln, row = (reg&3) + 8*(reg>>2) + 4*kb
    // ---------------- epilogues ----------------
    if constexpr (MODE == 0) {
        float* C = (float*)C0 + (long)bz * sC;
#pragma unroll
        for (int mi = 0; mi < 4; ++mi)
#pragma unroll
            for (int reg = 0; reg < 16; ++reg) {
                int row = m0 + wr * 128 + mi * 32 + (reg & 3) + 8 * (reg >> 2) + 4 * kb;
#pragma unroll
                for (int nj = 0; nj < 2; ++nj)
                    C[(long)row * 1024 + n0 + wc * 64 + nj * 32 + ln] =
                        acc[mi][nj][reg];
            }
    } else if constexpr (!TRANSP) {
        ushort* C = (ushort*)C0 + (long)bz * sC;
#pragma unroll
        for (int mi = 0; mi < 4; ++mi)
#pragma unroll
            for (int reg = 0; reg < 16; ++reg) {
                int row = m0 + wr * 128 + mi * 32 + (reg & 3) + 8 * (reg >> 2) + 4 * kb;
                float s = SCALE ? exp2f(coef * (float)(row & 1023)) : 1.0f;
#pragma unroll
                for (int nj = 0; nj < 2; ++nj)
                    C[(long)row * 1024 + n0 + wc * 64 + nj * 32 + ln] =
                        f2b(acc[mi][nj][reg] * s);
            }
    } else {
        // transposed store: bounce whole 256x256 tile through LDS with
        // chunk-XOR swizzle (slot = chunk ^ (cn&31)) -> conflict-free both
        // sides, then fully coalesced ushort8 readout.  out[b][d][s]
        ushort* Tl = (ushort*)lds;
        const int bb = m0 >> 10;          // batch index
        const int ms = m0 & 1023;         // s-offset within batch
        ushort* Ct = (ushort*)C0 + (long)bb * sC;
#pragma unroll
        for (int mi = 0; mi < 4; ++mi)
#pragma unroll
            for (int reg = 0; reg < 16; ++reg) {
                int rm = wr * 128 + mi * 32 + (reg & 3) + 8 * (reg >> 2) + 4 * kb;
                float s = SCALE ? exp2f(coef * (float)(ms + rm)) : 1.0f;
#pragma unroll
                for (int nj = 0; nj < 2; ++nj) {
                    int cn = wc * 64 + nj * 32 + ln;
                    int p  = (rm >> 3) ^ (cn & 31);
                    Tl[cn * 256 + p * 8 + (rm & 7)] = f2b(acc[mi][nj][reg] * s);
                }
            }
        __syncthreads();
#pragma unroll
        for (int it = 0; it < 16; ++it) {
            int cn = (t >> 5) + it * 16;
            int ch = t & 31;
            int p  = ch ^ (cn & 31);
            ushort8 v = *(const ushort8*)&Tl[cn * 256 + p * 8];
            *(ushort8*)&Ct[(long)(n0 + cn) * 1024 + ms + ch * 8] = v;
        }
    }
}

// ---------------- prepass: fp32 -> bf16 convert ----------------
__global__ __launch_bounds__(256)
void conv_x_k(const float* __restrict__ x, ushort* __restrict__ xb)
{
    long i = ((long)blockIdx.x * 256 + threadIdx.x) * 8;
    float4 a = *(const float4*)&x[i];
    float4 b = *(const float4*)&x[i + 4];
    ushort8 v;
    v[0] = f2b(a.x); v[1] = f2b(a.y); v[2] = f2b(a.z); v[3] = f2b(a.w);
    v[4] = f2b(b.x); v[5] = f2b(b.y); v[6] = f2b(b.z); v[7] = f2b(b.w);
    *(ushort8*)&xb[i] = v;
}

// ---------------- prepass: weight transpose + convert ----------------
__global__ __launch_bounds__(256)
void wt_k(const float* __restrict__ W, ushort* __restrict__ Wt)
{
    __shared__ float Tl[32][33];
    int tx = threadIdx.x & 31, ty = threadIdx.x >> 5;
    int c0 = blockIdx.x * 32, r0 = blockIdx.y * 32;
#pragma unroll
    for (int i = 0; i < 4; i++)
        Tl[ty + 8 * i][tx] = W[(long)(r0 + ty + 8 * i) * 1024 + c0 + tx];
    __syncthreads();
#pragma unroll
    for (int i = 0; i < 4; i++)
        Wt[(long)(c0 + ty + 8 * i) * 1024 + r0 + tx] = f2b(Tl[tx][ty + 8 * i]);
}

// ---------------- GroupNorm over seq axis ----------------
__global__ __launch_bounds__(256)
void stats1(const float* __restrict__ y, float* __restrict__ psum,
            float* __restrict__ psumsq)
{
    int d = blockIdx.x * 256 + threadIdx.x;
    int b = blockIdx.y;
    int z = blockIdx.z;
    const float* p = y + ((long)b * SN_ + (long)z * 128) * DN_ + d;
    float s = 0.f, ss = 0.f;
    for (int i = 0; i < 128; i++) {
        float v = p[(long)i * DN_];
        s += v;
        ss += v * v;
    }
    long o = ((long)z * BATCH_ + b) * DN_ + d;
    psum[o] = s;
    psumsq[o] = ss;
}

__global__ __launch_bounds__(256)
void stats2(const float* __restrict__ psum, const float* __restrict__ psumsq,
            const float* __restrict__ gsc, const float* __restrict__ gbt,
            float* __restrict__ fs, float* __restrict__ bias)
{
    int d = blockIdx.x * 256 + threadIdx.x;
    int b = blockIdx.y;
    float s = 0.f, ss = 0.f;
    for (int z = 0; z < 8; z++) {
        long o = ((long)z * BATCH_ + b) * DN_ + d;
        s += psum[o];
        ss += psumsq[o];
    }
    float mean = s * (1.0f / SN_);
    float var  = ss * (1.0f / SN_) - mean * mean;
    var = fmaxf(var, 0.0f);
    float rstd = rsqrtf(var + EPS_);
    float f = rstd * gsc[d];
    fs[(long)b * DN_ + d]   = f;
    bias[(long)b * DN_ + d] = gbt[d] - mean * f;
}

__global__ __launch_bounds__(256)
void norm_k(float* __restrict__ y, const float* __restrict__ fs,
            const float* __restrict__ bias)
{
    long i4 = (long)blockIdx.x * 256 + threadIdx.x;
    long e  = i4 * 4;
    int d = (int)(e & (DN_ - 1));
    int b = (int)(e >> 20);
    float4 v = *(float4*)&y[e];
    long o = (long)b * DN_ + d;
    float4 f  = *(const float4*)&fs[o];
    float4 bb = *(const float4*)&bias[o];
    v.x = v.x * f.x + bb.x;
    v.y = v.y * f.y + bb.y;
    v.z = v.z * f.z + bb.z;
    v.w = v.w * f.w + bb.w;
    *(float4*)&y[e] = v;
}

extern "C" void kernel_launch(void* const* d_in, const int* in_sizes, int n_in,
                              void* d_out, int out_size, void* d_ws, size_t ws_size,
                              hipStream_t stream)
{
    const float* x   = (const float*)d_in[0];
    const float* Wq  = (const float*)d_in[1];
    const float* Wk  = (const float*)d_in[2];
    const float* Wv  = (const float*)d_in[3];
    const float* gsc = (const float*)d_in[4];
    const float* gbt = (const float*)d_in[5];
    float* out = (float*)d_out;

    const long SD = (long)SN_ * DN_;
    const long DD = (long)DN_ * DN_;
    const size_t MB32 = (size_t)SD * BATCH_ * sizeof(ushort);  // 32 MiB

    char* ws = (char*)d_ws;
    ushort* xb  = (ushort*)(ws);
    ushort* Qp  = (ushort*)(ws + 1 * MB32);
    ushort* Kt  = (ushort*)(ws + 2 * MB32);
    ushort* Vt  = (ushort*)(ws + 3 * MB32);
    ushort* Mt  = (ushort*)(ws + 4 * MB32);
    ushort* Wtq = (ushort*)(ws + 5 * MB32);
    ushort* Wtk = (ushort*)(ws + 5 * MB32 + (2u << 20));
    ushort* Wtv = (ushort*)(ws + 5 * MB32 + (4u << 20));
    float*  psum   = (float*)(ws + 5 * MB32 + (6u << 20));
    float*  psumsq = (float*)(ws + 5 * MB32 + (6u << 20) + (1u << 19));
    float*  fs     = (float*)(ws + 5 * MB32 + (7u << 20));
    float*  bias   = (float*)(ws + 5 * MB32 + (7u << 20) + (1u << 18));

    const float lgf = (float)log2(0.96875);  // log2(gamma)

    dim3 blk512(512);
    dim3 blk(256);
    dim3 gproj(4, 64);      // N=1024/256, M=16384/256 (batch folded into M)
    dim3 gmt(4, 4, 16);     // per-batch 1024x1024
    dim3 gy(4, 64);

    // prepass
    conv_x_k<<<dim3(8192), blk, 0, stream>>>(x, xb);
    wt_k<<<dim3(32, 32), blk, 0, stream>>>(Wq, Wtq);
    wt_k<<<dim3(32, 32), blk, 0, stream>>>(Wk, Wtk);
    wt_k<<<dim3(32, 32), blk, 0, stream>>>(Wv, Wtv);

    // Q' = (x Wq) * gamma^s            [B*S][D] bf16
    gemm_bf<1><<<gproj, blk512, 0, stream>>>(xb, Wtq, Qp, 0, 0, 0, 0, lgf);
    // K't = ((x Wk) * gamma^-s)^T      [B][D][S] bf16
    gemm_bf<3><<<gproj, blk512, 0, stream>>>(xb, Wtk, Kt, 0, 0, 0, SD, -lgf);
    // V't = (x Wv)^T                   [B][D][S] bf16
    gemm_bf<2><<<gproj, blk512, 0, stream>>>(xb, Wtv, Vt, 0, 0, 0, SD, 0.0f);
    // Mt = V't x Kt(B^T) = M^T         [B][D][D] bf16
    gemm_bf<4><<<gmt, blk512, 0, stream>>>(Vt, Kt, Mt, SD, SD, 0, DD, 0.0f);
    // y = Q' x Mt(B^T, per-batch) = Q' M   [B*S][D] fp32 -> d_out
    gemm_bf<0><<<gy, blk512, 0, stream>>>(Qp, Mt, out, 0, 0, DD, 0, 0.0f);

    // GroupNorm over seq per (b, channel)
    stats1<<<dim3(4, 16, 8), blk, 0, stream>>>(out, psum, psumsq);
    stats2<<<dim3(4, 16), blk, 0, stream>>>(psum, psumsq, gsc, gbt, fs, bias);
    norm_k<<<dim3(16384), blk, 0, stream>>>(out, fs, bias);
}

// Round 5
// 261.142 us; speedup vs baseline: 7.8332x; 1.0090x over previous
//
#include <hip/hip_runtime.h>
#include <cmath>

#define BATCH_ 16
#define SN_ 1024
#define DN_ 1024

constexpr float EPS_ = 1e-3f;

typedef unsigned short ushort;
typedef __attribute__((ext_vector_type(8))) short short8;
typedef __attribute__((ext_vector_type(8))) unsigned short ushort8;
typedef __attribute__((ext_vector_type(16))) float f32x16;

__device__ __forceinline__ ushort f2b(float f) {
    unsigned u = __float_as_uint(f);
    unsigned r = (u + 0x7fffu + ((u >> 16) & 1u)) >> 16;
    return (ushort)r;
}

__device__ __forceinline__ void gload16(const void* g, void* l) {
    __builtin_amdgcn_global_load_lds(
        (const __attribute__((address_space(1))) void*)g,
        (__attribute__((address_space(3))) void*)l, 16, 0, 0);
}

#define SCHED0 __builtin_amdgcn_sched_barrier(0)
#define CFENCE asm volatile("" ::: "memory")

// ---------------------------------------------------------------------------
// bf16 MFMA GEMM, 256x256 tile, BK=64, 512 thr (8 waves, 2Mx4N),
// v_mfma_f32_32x32x16_bf16, double-buffered 128 KiB LDS, 4-phase K-step with
// counted vmcnt (T3+T4), raw s_barrier (no vmcnt drain), setprio (T5),
// chunk-XOR LDS swizzle (T2), bijective XCD swizzle (T1).
// LDS per buffer: A [256 rows][64 k] bf16 at +0, B same at +32KB; chunk c
// (16B) of row r stored at phys slot (c ^ (r&7)).
// Staging chunks (8KB, 64 rows): issue order B0,B1,B2,B3,A0,A2,A1,A3.
// Phase p computes mi=p (A rows wr*128+p*32..+32): phases 0,1 read A0,A2;
// phases 2,3 read A1,A3; B read fully in phase 0, held in regs.
// vmcnt proof: tile t p3-end vmcnt(2) -> t+1's first 6 chunks landed
// (B0-3,A0,A2 = needs of t+1 p0/p1); t p1-end vmcnt(4) -> t's A1,A3 landed
// (needs of t p2/p3); kt==15 uses vmcnt(0) at p1 (no newer loads exist).
// A row-major [M][K], B in B^T layout [N][K], K = 1024.
// MODE 0: fp32 out plain              (y = Q' Mt)
// MODE 1: bf16 out, row-scale         (Q')
// MODE 2: bf16 out, transposed        (V't)
// MODE 3: bf16 out, transposed+scale  (K't)
// MODE 4: bf16 out plain              (Mt)
// ---------------------------------------------------------------------------
template<int MODE>
__global__ __launch_bounds__(512, 2)
void gemm_bf(const ushort* __restrict__ A0, const ushort* __restrict__ B0,
             void* __restrict__ C0, long sA, long sB, long sBm, long sC,
             float coef)
{
    constexpr bool TRANSP = (MODE == 2 || MODE == 3);
    constexpr bool SCALE  = (MODE == 1 || MODE == 3);

    __shared__ __align__(16) char lds[131072];  // 2 bufs x (A 32K + B 32K)

    // ---- bijective XCD swizzle (total blocks == 256, % 8 == 0) ----
    const int gx = gridDim.x, gy = gridDim.y;
    int lid   = blockIdx.x + gx * (blockIdx.y + gy * blockIdx.z);
    int total = gx * gy * gridDim.z;
    int swz   = (lid & 7) * (total >> 3) + (lid >> 3);
    int bx = swz % gx;
    int rest = swz / gx;
    int by = rest % gy;
    int bz = rest / gy;

    const int m0 = by * 256, n0 = bx * 256;
    const ushort* A  = A0 + (long)bz * sA;
    const ushort* Bp = B0 + (long)bz * sB + (long)(m0 >> 10) * sBm;

    const int t = threadIdx.x;
    const int l = t & 63, w = t >> 6;
    const int wr = w >> 2, wc = w & 3;    // wave grid 2M x 4N
    const int ln = l & 31;                // MFMA row/col lane
    const int kb = l >> 5;                // k half (0/1)
    const int lx = l & 7;                 // swizzle xor for frag reads

    // frag-read lane bases (byte offsets inside a buffer)
    const int aOff = (wr * 128 + ln) * 128;
    const int bOff = 32768 + (wc * 64 + ln) * 128;
    int sx[4];
#pragma unroll
    for (int ks = 0; ks < 4; ++ks) sx[ks] = (((ks * 2) + kb) ^ lx) * 16;

    // ---- staging: thread t writes 16B at linear LDS t*16; source address
    //      pre-swizzled so phys slot s of row r holds chunk (s ^ (r&7)).
    const int rl   = t >> 3;                 // row within 64-row chunk
    const int slot = (t & 7) ^ (rl & 7);
    const ushort* gA = A  + (long)(m0 + rl) * 1024 + slot * 8;
    const ushort* gB = Bp + (long)(n0 + rl) * 1024 + slot * 8;
    char* lA = lds + t * 16;                 // + buf + h*8192
    char* lB = lds + 32768 + t * 16;

#define STA(h, k0, bo_) gload16(gA + (long)(h) * 65536 + (k0), lA + (bo_) + (h) * 8192)
#define STB(h, k0, bo_) gload16(gB + (long)(h) * 65536 + (k0), lB + (bo_) + (h) * 8192)

    f32x16 acc[4][2] = {};

    // ---- prologue: stage tile 0 into buf 0 ----
    STB(0, 0, 0); STB(1, 0, 0); STB(2, 0, 0); STB(3, 0, 0);
    STA(0, 0, 0); STA(2, 0, 0); STA(1, 0, 0); STA(3, 0, 0);
    SCHED0;
    asm volatile("s_waitcnt vmcnt(2)" ::: "memory");
    __builtin_amdgcn_s_barrier();
    CFENCE; SCHED0;

    for (int kt = 0; kt < 16; ++kt) {
        const int bo = (kt & 1) << 16;
        const int bn = bo ^ 65536;
        const int k1 = (kt + 1) << 6;
        const bool st = kt < 15;

        short8 bv[2][4], av[4];

        // ========== phase 0 : mi=0, read all B frags; stage B0,B1 ==========
#pragma unroll
        for (int ks = 0; ks < 4; ++ks) {
            bv[0][ks] = *(const short8*)(lds + bo + bOff + 0 * 4096 + sx[ks]);
            bv[1][ks] = *(const short8*)(lds + bo + bOff + 1 * 4096 + sx[ks]);
            av[ks]    = *(const short8*)(lds + bo + aOff + 0 * 4096 + sx[ks]);
        }
        if (st) { STB(0, k1, bn); STB(1, k1, bn); }
        SCHED0;
        __builtin_amdgcn_s_barrier();
        CFENCE; SCHED0;
        __builtin_amdgcn_s_setprio(1);
#pragma unroll
        for (int ks = 0; ks < 4; ++ks) {
            acc[0][0] = __builtin_amdgcn_mfma_f32_32x32x16_bf16(
                av[ks], bv[0][ks], acc[0][0], 0, 0, 0);
            acc[0][1] = __builtin_amdgcn_mfma_f32_32x32x16_bf16(
                av[ks], bv[1][ks], acc[0][1], 0, 0, 0);
        }
        __builtin_amdgcn_s_setprio(0);
        SCHED0;
        __builtin_amdgcn_s_barrier();
        CFENCE; SCHED0;

        // ========== phase 1 : mi=1; stage B2,B3; tail vmcnt ==========
#pragma unroll
        for (int ks = 0; ks < 4; ++ks)
            av[ks] = *(const short8*)(lds + bo + aOff + 1 * 4096 + sx[ks]);
        if (st) { STB(2, k1, bn); STB(3, k1, bn); }
        SCHED0;
        __builtin_amdgcn_s_barrier();
        CFENCE; SCHED0;
        __builtin_amdgcn_s_setprio(1);
#pragma unroll
        for (int ks = 0; ks < 4; ++ks) {
            acc[1][0] = __builtin_amdgcn_mfma_f32_32x32x16_bf16(
                av[ks], bv[0][ks], acc[1][0], 0, 0, 0);
            acc[1][1] = __builtin_amdgcn_mfma_f32_32x32x16_bf16(
                av[ks], bv[1][ks], acc[1][1], 0, 0, 0);
        }
        __builtin_amdgcn_s_setprio(0);
        SCHED0;
        if (kt == 15) asm volatile("s_waitcnt vmcnt(0)" ::: "memory");
        else          asm volatile("s_waitcnt vmcnt(4)" ::: "memory");
        __builtin_amdgcn_s_barrier();
        CFENCE; SCHED0;

        // ========== phase 2 : mi=2; stage A0,A2 ==========
#pragma unroll
        for (int ks = 0; ks < 4; ++ks)
            av[ks] = *(const short8*)(lds + bo + aOff + 2 * 4096 + sx[ks]);
        if (st) { STA(0, k1, bn); STA(2, k1, bn); }
        SCHED0;
        __builtin_amdgcn_s_barrier();
        CFENCE; SCHED0;
        __builtin_amdgcn_s_setprio(1);
#pragma unroll
        for (int ks = 0; ks < 4; ++ks) {
            acc[2][0] = __builtin_amdgcn_mfma_f32_32x32x16_bf16(
                av[ks], bv[0][ks], acc[2][0], 0, 0, 0);
            acc[2][1] = __builtin_amdgcn_mfma_f32_32x32x16_bf16(
                av[ks], bv[1][ks], acc[2][1], 0, 0, 0);
        }
        __builtin_amdgcn_s_setprio(0);
        SCHED0;
        __builtin_amdgcn_s_barrier();
        CFENCE; SCHED0;

        // ========== phase 3 : mi=3; stage A1,A3; tail vmcnt(2) ==========
#pragma unroll
        for (int ks = 0; ks < 4; ++ks)
            av[ks] = *(const short8*)(lds + bo + aOff + 3 * 4096 + sx[ks]);
        if (st) { STA(1, k1, bn); STA(3, k1, bn); }
        SCHED0;
        __builtin_amdgcn_s_barrier();
        CFENCE; SCHED0;
        __builtin_amdgcn_s_setprio(1);
#pragma unroll
        for (int ks = 0; ks < 4; ++ks) {
            acc[3][0] = __builtin_amdgcn_mfma_f32_32x32x16_bf16(
                av[ks], bv[0][ks], acc[3][0], 0, 0, 0);
            acc[3][1] = __builtin_amdgcn_mfma_f32_32x32x16_bf16(
                av[ks], bv[1][ks], acc[3][1], 0, 0, 0);
        }
        __builtin_amdgcn_s_setprio(0);
        SCHED0;
        asm volatile("s_waitcnt vmcnt(2)" ::: "memory");
        __builtin_amdgcn_s_barrier();
        CFENCE; SCHED0;
    }

    // C/D 32x32 layout: col = ln, row = (reg&3) + 8*(reg>>2) + 4*kb
    // ---------------- epilogues ----------------
    if constexpr (MODE == 0) {
        float* C = (float*)C0 + (long)bz * sC;
#pragma unroll
        for (int mi = 0; mi < 4; ++mi)
#pragma unroll
            for (int reg = 0; reg < 16; ++reg) {
                int row = m0 + wr * 128 + mi * 32 + (reg & 3) + 8 * (reg >> 2) + 4 * kb;
#pragma unroll
                for (int nj = 0; nj < 2; ++nj)
                    C[(long)row * 1024 + n0 + wc * 64 + nj * 32 + ln] =
                        acc[mi][nj][reg];
            }
    } else if constexpr (!TRANSP) {
        ushort* C = (ushort*)C0 + (long)bz * sC;
#pragma unroll
        for (int mi = 0; mi < 4; ++mi)
#pragma unroll
            for (int reg = 0; reg < 16; ++reg) {
                int row = m0 + wr * 128 + mi * 32 + (reg & 3) + 8 * (reg >> 2) + 4 * kb;
                float s = SCALE ? exp2f(coef * (float)(row & 1023)) : 1.0f;
#pragma unroll
                for (int nj = 0; nj < 2; ++nj)
                    C[(long)row * 1024 + n0 + wc * 64 + nj * 32 + ln] =
                        f2b(acc[mi][nj][reg] * s);
            }
    } else {
        // transposed store: bounce whole 256x256 tile through LDS with
        // chunk-XOR swizzle (slot = chunk ^ (cn&31)) -> conflict-free both
        // sides, then fully coalesced ushort8 readout.  out[b][d][s]
        ushort* Tl = (ushort*)lds;
        const int bb = m0 >> 10;          // batch index
        const int ms = m0 & 1023;         // s-offset within batch
        ushort* Ct = (ushort*)C0 + (long)bb * sC;
        __syncthreads();
#pragma unroll
        for (int mi = 0; mi < 4; ++mi)
#pragma unroll
            for (int reg = 0; reg < 16; ++reg) {
                int rm = wr * 128 + mi * 32 + (reg & 3) + 8 * (reg >> 2) + 4 * kb;
                float s = SCALE ? exp2f(coef * (float)(ms + rm)) : 1.0f;
#pragma unroll
                for (int nj = 0; nj < 2; ++nj) {
                    int cn = wc * 64 + nj * 32 + ln;
                    int p  = (rm >> 3) ^ (cn & 31);
                    Tl[cn * 256 + p * 8 + (rm & 7)] = f2b(acc[mi][nj][reg] * s);
                }
            }
        __syncthreads();
#pragma unroll
        for (int it = 0; it < 16; ++it) {
            int cn = (t >> 5) + it * 16;
            int ch = t & 31;
            int p  = ch ^ (cn & 31);
            ushort8 v = *(const ushort8*)&Tl[cn * 256 + p * 8];
            *(ushort8*)&Ct[(long)(n0 + cn) * 1024 + ms + ch * 8] = v;
        }
    }
#undef STA
#undef STB
}

// ---------------- prepass: fp32 -> bf16 convert ----------------
__global__ __launch_bounds__(256)
void conv_x_k(const float* __restrict__ x, ushort* __restrict__ xb)
{
    long i = ((long)blockIdx.x * 256 + threadIdx.x) * 8;
    float4 a = *(const float4*)&x[i];
    float4 b = *(const float4*)&x[i + 4];
    ushort8 v;
    v[0] = f2b(a.x); v[1] = f2b(a.y); v[2] = f2b(a.z); v[3] = f2b(a.w);
    v[4] = f2b(b.x); v[5] = f2b(b.y); v[6] = f2b(b.z); v[7] = f2b(b.w);
    *(ushort8*)&xb[i] = v;
}

// ---------------- prepass: weight transpose + convert ----------------
__global__ __launch_bounds__(256)
void wt_k(const float* __restrict__ W, ushort* __restrict__ Wt)
{
    __shared__ float Tl[32][33];
    int tx = threadIdx.x & 31, ty = threadIdx.x >> 5;
    int c0 = blockIdx.x * 32, r0 = blockIdx.y * 32;
#pragma unroll
    for (int i = 0; i < 4; i++)
        Tl[ty + 8 * i][tx] = W[(long)(r0 + ty + 8 * i) * 1024 + c0 + tx];
    __syncthreads();
#pragma unroll
    for (int i = 0; i < 4; i++)
        Wt[(long)(c0 + ty + 8 * i) * 1024 + r0 + tx] = f2b(Tl[tx][ty + 8 * i]);
}

// ---------------- GroupNorm over seq axis ----------------
__global__ __launch_bounds__(256)
void stats1(const float* __restrict__ y, float* __restrict__ psum,
            float* __restrict__ psumsq)
{
    int d = blockIdx.x * 256 + threadIdx.x;
    int b = blockIdx.y;
    int z = blockIdx.z;
    const float* p = y + ((long)b * SN_ + (long)z * 128) * DN_ + d;
    float s = 0.f, ss = 0.f;
    for (int i = 0; i < 128; i++) {
        float v = p[(long)i * DN_];
        s += v;
        ss += v * v;
    }
    long o = ((long)z * BATCH_ + b) * DN_ + d;
    psum[o] = s;
    psumsq[o] = ss;
}

__global__ __launch_bounds__(256)
void stats2(const float* __restrict__ psum, const float* __restrict__ psumsq,
            const float* __restrict__ gsc, const float* __restrict__ gbt,
            float* __restrict__ fs, float* __restrict__ bias)
{
    int d = blockIdx.x * 256 + threadIdx.x;
    int b = blockIdx.y;
    float s = 0.f, ss = 0.f;
    for (int z = 0; z < 8; z++) {
        long o = ((long)z * BATCH_ + b) * DN_ + d;
        s += psum[o];
        ss += psumsq[o];
    }
    float mean = s * (1.0f / SN_);
    float var  = ss * (1.0f / SN_) - mean * mean;
    var = fmaxf(var, 0.0f);
    float rstd = rsqrtf(var + EPS_);
    float f = rstd * gsc[d];
    fs[(long)b * DN_ + d]   = f;
    bias[(long)b * DN_ + d] = gbt[d] - mean * f;
}

__global__ __launch_bounds__(256)
void norm_k(float* __restrict__ y, const float* __restrict__ fs,
            const float* __restrict__ bias)
{
    long i4 = (long)blockIdx.x * 256 + threadIdx.x;
    long e  = i4 * 4;
    int d = (int)(e & (DN_ - 1));
    int b = (int)(e >> 20);
    float4 v = *(float4*)&y[e];
    long o = (long)b * DN_ + d;
    float4 f  = *(const float4*)&fs[o];
    float4 bb = *(const float4*)&bias[o];
    v.x = v.x * f.x + bb.x;
    v.y = v.y * f.y + bb.y;
    v.z = v.z * f.z + bb.z;
    v.w = v.w * f.w + bb.w;
    *(float4*)&y[e] = v;
}

extern "C" void kernel_launch(void* const* d_in, const int* in_sizes, int n_in,
                              void* d_out, int out_size, void* d_ws, size_t ws_size,
                              hipStream_t stream)
{
    const float* x   = (const float*)d_in[0];
    const float* Wq  = (const float*)d_in[1];
    const float* Wk  = (const float*)d_in[2];
    const float* Wv  = (const float*)d_in[3];
    const float* gsc = (const float*)d_in[4];
    const float* gbt = (const float*)d_in[5];
    float* out = (float*)d_out;

    const long SD = (long)SN_ * DN_;
    const long DD = (long)DN_ * DN_;
    const size_t MB32 = (size_t)SD * BATCH_ * sizeof(ushort);  // 32 MiB

    char* ws = (char*)d_ws;
    ushort* xb  = (ushort*)(ws);
    ushort* Qp  = (ushort*)(ws + 1 * MB32);
    ushort* Kt  = (ushort*)(ws + 2 * MB32);
    ushort* Vt  = (ushort*)(ws + 3 * MB32);
    ushort* Mt  = (ushort*)(ws + 4 * MB32);
    ushort* Wtq = (ushort*)(ws + 5 * MB32);
    ushort* Wtk = (ushort*)(ws + 5 * MB32 + (2u << 20));
    ushort* Wtv = (ushort*)(ws + 5 * MB32 + (4u << 20));
    float*  psum   = (float*)(ws + 5 * MB32 + (6u << 20));
    float*  psumsq = (float*)(ws + 5 * MB32 + (6u << 20) + (1u << 19));
    float*  fs     = (float*)(ws + 5 * MB32 + (7u << 20));
    float*  bias   = (float*)(ws + 5 * MB32 + (7u << 20) + (1u << 18));

    const float lgf = (float)log2(0.96875);  // log2(gamma)

    dim3 blk512(512);
    dim3 blk(256);
    dim3 gproj(4, 64);      // N=1024/256, M=16384/256 (batch folded into M)
    dim3 gmt(4, 4, 16);     // per-batch 1024x1024
    dim3 gy(4, 64);

    // prepass
    conv_x_k<<<dim3(8192), blk, 0, stream>>>(x, xb);
    wt_k<<<dim3(32, 32), blk, 0, stream>>>(Wq, Wtq);
    wt_k<<<dim3(32, 32), blk, 0, stream>>>(Wk, Wtk);
    wt_k<<<dim3(32, 32), blk, 0, stream>>>(Wv, Wtv);

    // Q' = (x Wq) * gamma^s            [B*S][D] bf16
    gemm_bf<1><<<gproj, blk512, 0, stream>>>(xb, Wtq, Qp, 0, 0, 0, 0, lgf);
    // K't = ((x Wk) * gamma^-s)^T      [B][D][S] bf16
    gemm_bf<3><<<gproj, blk512, 0, stream>>>(xb, Wtk, Kt, 0, 0, 0, SD, -lgf);
    // V't = (x Wv)^T                   [B][D][S] bf16
    gemm_bf<2><<<gproj, blk512, 0, stream>>>(xb, Wtv, Vt, 0, 0, 0, SD, 0.0f);
    // Mt = V't x Kt(B^T) = M^T         [B][D][D] bf16
    gemm_bf<4><<<gmt, blk512, 0, stream>>>(Vt, Kt, Mt, SD, SD, 0, DD, 0.0f);
    // y = Q' x Mt(B^T, per-batch) = Q' M   [B*S][D] fp32 -> d_out
    gemm_bf<0><<<gy, blk512, 0, stream>>>(Qp, Mt, out, 0, 0, DD, 0, 0.0f);

    // GroupNorm over seq per (b, channel)
    stats1<<<dim3(4, 16, 8), blk, 0, stream>>>(out, psum, psumsq);
    stats2<<<dim3(4, 16), blk, 0, stream>>>(psum, psumsq, gsc, gbt, fs, bias);
    norm_k<<<dim3(16384), blk, 0, stream>>>(out, fs, bias);
}

// Round 6
// 237.872 us; speedup vs baseline: 8.5994x; 1.0978x over previous
//
#include <hip/hip_runtime.h>
#include <cmath>

#define BATCH_ 16
#define SN_ 1024
#define DN_ 1024

constexpr float EPS_ = 1e-3f;

typedef unsigned short ushort;
typedef __attribute__((ext_vector_type(8))) short short8;
typedef __attribute__((ext_vector_type(8))) unsigned short ushort8;
typedef __attribute__((ext_vector_type(16))) float f32x16;

__device__ __forceinline__ ushort f2b(float f) {
    unsigned u = __float_as_uint(f);
    unsigned r = (u + 0x7fffu + ((u >> 16) & 1u)) >> 16;
    return (ushort)r;
}

__device__ __forceinline__ void gload16(const void* g, void* l) {
    __builtin_amdgcn_global_load_lds(
        (const __attribute__((address_space(1))) void*)g,
        (__attribute__((address_space(3))) void*)l, 16, 0, 0);
}

#define SCHED0 __builtin_amdgcn_sched_barrier(0)
#define MFMA32(a, b, c) __builtin_amdgcn_mfma_f32_32x32x16_bf16(a, b, c, 0, 0, 0)

// ---------------------------------------------------------------------------
// bf16 MFMA GEMM, 256x256 tile, BK=64, 512 thr (8 waves, 2Mx4N),
// v_mfma_f32_32x32x16_bf16, double-buffered 128 KiB LDS, chunk-XOR swizzle.
// K-step split into 4 k-phases (balanced: 6 ds_read_b128 + 8 MFMA each);
// NO intra-tile barriers (all waves read-only on live buffer; DMA writes go
// to the other buffer) -> waves free-run, LDS port and MFMA pipe overlap.
// One vmcnt(0)+s_barrier per tile boundary; all 8 prefetch chunks for tile
// t+1 issued in phases 0-1 of tile t, so ages at the boundary wait are
// >= ~1600 cyc > HBM latency.
// A row-major [M][K], B in B^T layout [N][K], K = 1024.
// MODE 4: bf16 out plain (Mt)
// MODE 5: bf16 out + per-block column sum/sumsq -> psum/psq[by][1024]  (y)
// MODE 6: merged projections, 3-way epilogue by n-block:
//         which=0 -> Qp (bf16, row-scale gamma^s)
//         which=1 -> Kt (bf16, transposed, scale gamma^-s)
//         which=2 -> Vt (bf16, transposed)
// ---------------------------------------------------------------------------
template<int MODE>
__global__ __launch_bounds__(512, 2)
void gemm_bf(const ushort* __restrict__ A0, const ushort* __restrict__ B0,
             void* __restrict__ C0, void* __restrict__ C1, void* __restrict__ C2,
             float* __restrict__ psum, float* __restrict__ psq,
             long sA, long sB, long sBm, long sC, float coef)
{
    __shared__ __align__(16) char lds[131072];  // 2 bufs x (A 32K + B 32K)

    // ---- bijective XCD swizzle (all grids are multiples of 8 blocks) ----
    const int gx = gridDim.x, gy = gridDim.y;
    int lid   = blockIdx.x + gx * (blockIdx.y + gy * blockIdx.z);
    int total = gx * gy * gridDim.z;
    int swz   = (lid & 7) * (total >> 3) + (lid >> 3);
    int bx = swz % gx;
    int rest = swz / gx;
    int by = rest % gy;
    int bz = rest / gy;

    const int m0 = by * 256, n0 = bx * 256;
    const ushort* A  = A0 + (long)bz * sA;
    const ushort* Bp = B0 + (long)bz * sB + (long)(m0 >> 10) * sBm;

    const int t = threadIdx.x;
    const int l = t & 63, w = t >> 6;
    const int wr = w >> 2, wc = w & 3;    // wave grid 2M x 4N
    const int ln = l & 31;                // MFMA row/col lane
    const int kb = l >> 5;                // k half (0/1)
    const int lx = l & 7;                 // swizzle xor for frag reads

    // frag-read lane bases (byte offsets inside a buffer)
    const int aOff = (wr * 128 + ln) * 128;
    const int bOff = 32768 + (wc * 64 + ln) * 128;

    // ---- staging: thread t writes 16B at linear LDS t*16; source address
    //      pre-swizzled so phys slot s of row r holds chunk (s ^ (r&7)).
    const int rl   = t >> 3;                 // row within 64-row chunk
    const int slot = (t & 7) ^ (rl & 7);
    const ushort* gA = A  + (long)(m0 + rl) * 1024 + slot * 8;
    const ushort* gB = Bp + (long)(n0 + rl) * 1024 + slot * 8;
    char* lA = lds + t * 16;                 // + buf + h*8192
    char* lB = lds + 32768 + t * 16;

#define STA(h, k0, bo_) gload16(gA + (long)(h) * 65536 + (k0), lA + (bo_) + (h) * 8192)
#define STB(h, k0, bo_) gload16(gB + (long)(h) * 65536 + (k0), lB + (bo_) + (h) * 8192)

    f32x16 acc[4][2] = {};

    // ---- prologue: stage tile 0 into buf 0 ----
    STB(0, 0, 0); STB(1, 0, 0); STB(2, 0, 0); STB(3, 0, 0);
    STA(0, 0, 0); STA(1, 0, 0); STA(2, 0, 0); STA(3, 0, 0);
    SCHED0;
    asm volatile("s_waitcnt vmcnt(0)" ::: "memory");
    SCHED0;
    __builtin_amdgcn_s_barrier();
    SCHED0;

    for (int kt = 0; kt < 16; ++kt) {
        const int bo = (kt & 1) << 16;
        const int bn = bo ^ 65536;
        const int k1 = (kt + 1) << 6;
        const bool st = kt < 15;
        const char* base = lds + bo;

#pragma unroll
        for (int p = 0; p < 4; ++p) {
            const int sxp = ((p * 2 + kb) ^ lx) * 16;
            short8 a0 = *(const short8*)(base + aOff + 0 * 4096 + sxp);
            short8 a1 = *(const short8*)(base + aOff + 1 * 4096 + sxp);
            short8 a2 = *(const short8*)(base + aOff + 2 * 4096 + sxp);
            short8 a3 = *(const short8*)(base + aOff + 3 * 4096 + sxp);
            short8 b0 = *(const short8*)(base + bOff + 0 * 4096 + sxp);
            short8 b1 = *(const short8*)(base + bOff + 1 * 4096 + sxp);
            if (st) {
                if (p == 0) { STB(0, k1, bn); STB(1, k1, bn);
                              STB(2, k1, bn); STB(3, k1, bn); }
                else if (p == 1) { STA(0, k1, bn); STA(1, k1, bn);
                                   STA(2, k1, bn); STA(3, k1, bn); }
            }
            __builtin_amdgcn_s_setprio(1);
            acc[0][0] = MFMA32(a0, b0, acc[0][0]);
            acc[0][1] = MFMA32(a0, b1, acc[0][1]);
            acc[1][0] = MFMA32(a1, b0, acc[1][0]);
            acc[1][1] = MFMA32(a1, b1, acc[1][1]);
            acc[2][0] = MFMA32(a2, b0, acc[2][0]);
            acc[2][1] = MFMA32(a2, b1, acc[2][1]);
            acc[3][0] = MFMA32(a3, b0, acc[3][0]);
            acc[3][1] = MFMA32(a3, b1, acc[3][1]);
            __builtin_amdgcn_s_setprio(0);
            SCHED0;
        }
        // tile boundary: own prefetch landed + all waves done reading bo
        asm volatile("s_waitcnt vmcnt(0)" ::: "memory");
        SCHED0;
        __builtin_amdgcn_s_barrier();
        SCHED0;
    }

    // C/D 32x32 layout: col = ln, row = (reg&3) + 8*(reg>>2) + 4*kb
    // ---------------- epilogues ----------------
    if constexpr (MODE == 4) {
        ushort* C = (ushort*)C0 + (long)bz * sC;
#pragma unroll
        for (int mi = 0; mi < 4; ++mi)
#pragma unroll
            for (int reg = 0; reg < 16; ++reg) {
                int row = m0 + wr * 128 + mi * 32 + (reg & 3) + 8 * (reg >> 2) + 4 * kb;
#pragma unroll
                for (int nj = 0; nj < 2; ++nj)
                    C[(long)row * 1024 + n0 + wc * 64 + nj * 32 + ln] =
                        f2b(acc[mi][nj][reg]);
            }
    } else if constexpr (MODE == 5) {
        // bf16 y out + per-block column sums/sumsq (fused GroupNorm stats)
        ushort* C = (ushort*)C0;
        float cs0 = 0.f, cq0 = 0.f, cs1 = 0.f, cq1 = 0.f;
#pragma unroll
        for (int mi = 0; mi < 4; ++mi)
#pragma unroll
            for (int reg = 0; reg < 16; ++reg) {
                float v0 = acc[mi][0][reg], v1 = acc[mi][1][reg];
                cs0 += v0; cq0 += v0 * v0;
                cs1 += v1; cq1 += v1 * v1;
                int row = m0 + wr * 128 + mi * 32 + (reg & 3) + 8 * (reg >> 2) + 4 * kb;
                C[(long)row * 1024 + n0 + wc * 64 + ln]      = f2b(v0);
                C[(long)row * 1024 + n0 + wc * 64 + 32 + ln] = f2b(v1);
            }
        float* S4 = (float*)lds;            // [256 cols][4]
        float* Q4 = (float*)(lds + 4096);
        {
            int c0i = wc * 64 + ln, c1i = wc * 64 + 32 + ln, idx = wr * 2 + kb;
            S4[c0i * 4 + idx] = cs0; S4[c1i * 4 + idx] = cs1;
            Q4[c0i * 4 + idx] = cq0; Q4[c1i * 4 + idx] = cq1;
        }
        __syncthreads();
        if (t < 256) {
            float s = S4[t * 4] + S4[t * 4 + 1] + S4[t * 4 + 2] + S4[t * 4 + 3];
            float q = Q4[t * 4] + Q4[t * 4 + 1] + Q4[t * 4 + 2] + Q4[t * 4 + 3];
            psum[(long)by * 1024 + n0 + t] = s;
            psq [(long)by * 1024 + n0 + t] = q;
        }
    } else {
        // MODE 6: merged projections
        const int which = n0 >> 10;       // 0=Q, 1=K, 2=V
        const int nq = n0 & 1023;
        if (which == 0) {
            ushort* C = (ushort*)C0;
#pragma unroll
            for (int mi = 0; mi < 4; ++mi)
#pragma unroll
                for (int reg = 0; reg < 16; ++reg) {
                    int row = m0 + wr * 128 + mi * 32 + (reg & 3) + 8 * (reg >> 2) + 4 * kb;
                    float s = exp2f(coef * (float)(row & 1023));
#pragma unroll
                    for (int nj = 0; nj < 2; ++nj)
                        C[(long)row * 1024 + nq + wc * 64 + nj * 32 + ln] =
                            f2b(acc[mi][nj][reg] * s);
                }
        } else {
            // transposed store via LDS bounce (slot = chunk ^ (cn&31)),
            // fully coalesced ushort8 readout. out[b][d][s]
            ushort* Tl = (ushort*)lds;
            const int bb = m0 >> 10;          // batch index
            const int ms = m0 & 1023;         // s-offset within batch
            ushort* Ct = (ushort*)((which == 1) ? C1 : C2) + (long)bb * sC;
            const float cf = (which == 1) ? -coef : 0.0f;
            __syncthreads();
#pragma unroll
            for (int mi = 0; mi < 4; ++mi)
#pragma unroll
                for (int reg = 0; reg < 16; ++reg) {
                    int rm = wr * 128 + mi * 32 + (reg & 3) + 8 * (reg >> 2) + 4 * kb;
                    float s = exp2f(cf * (float)(ms + rm));
#pragma unroll
                    for (int nj = 0; nj < 2; ++nj) {
                        int cn = wc * 64 + nj * 32 + ln;
                        int p  = (rm >> 3) ^ (cn & 31);
                        Tl[cn * 256 + p * 8 + (rm & 7)] = f2b(acc[mi][nj][reg] * s);
                    }
                }
            __syncthreads();
#pragma unroll
            for (int it = 0; it < 16; ++it) {
                int cn = (t >> 5) + it * 16;
                int ch = t & 31;
                int p  = ch ^ (cn & 31);
                ushort8 v = *(const ushort8*)&Tl[cn * 256 + p * 8];
                *(ushort8*)&Ct[(long)(nq + cn) * 1024 + ms + ch * 8] = v;
            }
        }
    }
#undef STA
#undef STB
}

// ---------------- prepass: fp32 -> bf16 convert ----------------
__global__ __launch_bounds__(256)
void conv_x_k(const float* __restrict__ x, ushort* __restrict__ xb)
{
    long i = ((long)blockIdx.x * 256 + threadIdx.x) * 8;
    float4 a = *(const float4*)&x[i];
    float4 b = *(const float4*)&x[i + 4];
    ushort8 v;
    v[0] = f2b(a.x); v[1] = f2b(a.y); v[2] = f2b(a.z); v[3] = f2b(a.w);
    v[4] = f2b(b.x); v[5] = f2b(b.y); v[6] = f2b(b.z); v[7] = f2b(b.w);
    *(ushort8*)&xb[i] = v;
}

// ---------------- prepass: weight transpose + convert ----------------
__global__ __launch_bounds__(256)
void wt_k(const float* __restrict__ W, ushort* __restrict__ Wt)
{
    __shared__ float Tl[32][33];
    int tx = threadIdx.x & 31, ty = threadIdx.x >> 5;
    int c0 = blockIdx.x * 32, r0 = blockIdx.y * 32;
#pragma unroll
    for (int i = 0; i < 4; i++)
        Tl[ty + 8 * i][tx] = W[(long)(r0 + ty + 8 * i) * 1024 + c0 + tx];
    __syncthreads();
#pragma unroll
    for (int i = 0; i < 4; i++)
        Wt[(long)(c0 + ty + 8 * i) * 1024 + r0 + tx] = f2b(Tl[tx][ty + 8 * i]);
}

// ---------------- GroupNorm: finalize stats -> fused scale/bias ----------------
__global__ __launch_bounds__(256)
void stats2(const float* __restrict__ psum, const float* __restrict__ psq,
            const float* __restrict__ gsc, const float* __restrict__ gbt,
            float* __restrict__ fs, float* __restrict__ bias)
{
    int d = blockIdx.x * 256 + threadIdx.x;
    int b = blockIdx.y;
    float s = 0.f, q = 0.f;
#pragma unroll
    for (int z = 0; z < 4; z++) {
        long o = ((long)(b * 4 + z) << 10) + d;
        s += psum[o];
        q += psq[o];
    }
    float mean = s * (1.0f / SN_);
    float var  = q * (1.0f / SN_) - mean * mean;
    var = fmaxf(var, 0.0f);
    float rstd = rsqrtf(var + EPS_);
    float f = rstd * gsc[d];
    fs[(long)b * DN_ + d]   = f;
    bias[(long)b * DN_ + d] = gbt[d] - mean * f;
}

// ---------------- normalize: bf16 y -> fp32 out ----------------
__global__ __launch_bounds__(256)
void norm_k(const ushort* __restrict__ yb, const float* __restrict__ fs,
            const float* __restrict__ bias, float* __restrict__ out)
{
    long i = ((long)blockIdx.x * 256 + threadIdx.x) * 8;
    int d = (int)(i & (DN_ - 1));
    int b = (int)(i >> 20);
    ushort8 v = *(const ushort8*)&yb[i];
    long o = (long)b * DN_ + d;
    float4 f0 = *(const float4*)&fs[o];
    float4 f1 = *(const float4*)&fs[o + 4];
    float4 b0 = *(const float4*)&bias[o];
    float4 b1 = *(const float4*)&bias[o + 4];
    float4 o0, o1;
    o0.x = __uint_as_float((unsigned)v[0] << 16) * f0.x + b0.x;
    o0.y = __uint_as_float((unsigned)v[1] << 16) * f0.y + b0.y;
    o0.z = __uint_as_float((unsigned)v[2] << 16) * f0.z + b0.z;
    o0.w = __uint_as_float((unsigned)v[3] << 16) * f0.w + b0.w;
    o1.x = __uint_as_float((unsigned)v[4] << 16) * f1.x + b1.x;
    o1.y = __uint_as_float((unsigned)v[5] << 16) * f1.y + b1.y;
    o1.z = __uint_as_float((unsigned)v[6] << 16) * f1.z + b1.z;
    o1.w = __uint_as_float((unsigned)v[7] << 16) * f1.w + b1.w;
    *(float4*)&out[i]     = o0;
    *(float4*)&out[i + 4] = o1;
}

extern "C" void kernel_launch(void* const* d_in, const int* in_sizes, int n_in,
                              void* d_out, int out_size, void* d_ws, size_t ws_size,
                              hipStream_t stream)
{
    const float* x   = (const float*)d_in[0];
    const float* Wq  = (const float*)d_in[1];
    const float* Wk  = (const float*)d_in[2];
    const float* Wv  = (const float*)d_in[3];
    const float* gsc = (const float*)d_in[4];
    const float* gbt = (const float*)d_in[5];
    float* out = (float*)d_out;

    const long SD = (long)SN_ * DN_;
    const long DD = (long)DN_ * DN_;
    const size_t MB32 = (size_t)SD * BATCH_ * sizeof(ushort);  // 32 MiB

    char* ws = (char*)d_ws;
    ushort* xb  = (ushort*)(ws);            // x bf16; reused as yb after projs
    ushort* Qp  = (ushort*)(ws + 1 * MB32);
    ushort* Kt  = (ushort*)(ws + 2 * MB32);
    ushort* Vt  = (ushort*)(ws + 3 * MB32);
    ushort* Mt  = (ushort*)(ws + 4 * MB32);
    ushort* Wct = (ushort*)(ws + 5 * MB32);                       // [3072][1024] bf16
    float*  psum = (float*)(ws + 5 * MB32 + (6u << 20));          // [64][1024]
    float*  psq  = (float*)(ws + 5 * MB32 + (6u << 20) + (1u << 18));
    float*  fs   = (float*)(ws + 5 * MB32 + (6u << 20) + (2u << 18));
    float*  bias = (float*)(ws + 5 * MB32 + (6u << 20) + (2u << 18) + (1u << 16));
    ushort* yb  = xb;

    const float lgf = (float)log2(0.96875);  // log2(gamma)

    dim3 blk512(512);
    dim3 blk(256);
    dim3 gproj(12, 64);     // N=3072/256, M=16384/256  (768 blocks)
    dim3 gmt(4, 4, 16);     // per-batch 1024x1024      (256 blocks)
    dim3 gy(4, 64);         // N=1024/256, M=16384/256  (256 blocks)

    // prepass
    conv_x_k<<<dim3(8192), blk, 0, stream>>>(x, xb);
    wt_k<<<dim3(32, 32), blk, 0, stream>>>(Wq, Wct);
    wt_k<<<dim3(32, 32), blk, 0, stream>>>(Wk, Wct + 1024 * 1024);
    wt_k<<<dim3(32, 32), blk, 0, stream>>>(Wv, Wct + 2 * 1024 * 1024);

    // merged projections: Q' (scale gamma^s), K't (transp, gamma^-s), V't (transp)
    gemm_bf<6><<<gproj, blk512, 0, stream>>>(xb, Wct, Qp, Kt, Vt,
                                             nullptr, nullptr,
                                             0, 0, 0, SD, lgf);
    // Mt = V't x Kt(B^T) = M^T   [B][D][D] bf16
    gemm_bf<4><<<gmt, blk512, 0, stream>>>(Vt, Kt, Mt, nullptr, nullptr,
                                           nullptr, nullptr,
                                           SD, SD, 0, DD, 0.0f);
    // y = Q' x Mt(B^T per batch) -> bf16 yb + fused column stats
    gemm_bf<5><<<gy, blk512, 0, stream>>>(Qp, Mt, yb, nullptr, nullptr,
                                          psum, psq,
                                          0, 0, DD, 0, 0.0f);

    // GroupNorm finalize + apply
    stats2<<<dim3(4, 16), blk, 0, stream>>>(psum, psq, gsc, gbt, fs, bias);
    norm_k<<<dim3(8192), blk, 0, stream>>>(yb, fs, bias, out);
}

// Round 7
// 232.673 us; speedup vs baseline: 8.7916x; 1.0223x over previous
//
#include <hip/hip_runtime.h>
#include <cmath>

#define BATCH_ 16
#define SN_ 1024
#define DN_ 1024

constexpr float EPS_ = 1e-3f;

typedef unsigned short ushort;
typedef __attribute__((ext_vector_type(4))) unsigned short ushort4_t;
typedef __attribute__((ext_vector_type(8))) short short8;
typedef __attribute__((ext_vector_type(8))) unsigned short ushort8;
typedef __attribute__((ext_vector_type(16))) float f32x16;

__device__ __forceinline__ ushort f2b(float f) {
    unsigned u = __float_as_uint(f);
    unsigned r = (u + 0x7fffu + ((u >> 16) & 1u)) >> 16;
    return (ushort)r;
}

__device__ __forceinline__ void gload16(const void* g, void* l) {
    __builtin_amdgcn_global_load_lds(
        (const __attribute__((address_space(1))) void*)g,
        (__attribute__((address_space(3))) void*)l, 16, 0, 0);
}

#define SCHED0 __builtin_amdgcn_sched_barrier(0)
#define MFMA32(a, b, c) __builtin_amdgcn_mfma_f32_32x32x16_bf16(a, b, c, 0, 0, 0)

// ---------------------------------------------------------------------------
// bf16 MFMA GEMM, 256x256 tile, BK=64, 1024 thr (16 waves, 4Mx4N grid,
// wave tile 64x64 = 2x2 of 32x32), v_mfma_f32_32x32x16_bf16, double-buffered
// 128 KiB LDS, chunk-XOR swizzle (phys slot s of row r holds chunk s^(r&7)).
// One block/CU but 16 waves => 4 waves/SIMD (the round-6 config had only 2).
// K-tile split into 4 free-running k-phases (2 A + 2 B ds_read_b128 + 4 MFMA
// each, no intra-tile barriers: waves only read the live buffer; DMA writes
// go to the other buffer). One vmcnt(0)+s_barrier per tile boundary; the 4
// prefetch chunks are issued in phases 0-1 so they are ~2 phases old at the
// boundary wait.
// A row-major [M][K], B in B^T layout [N][K], K = 1024.
// MODE 4: bf16 out plain (Mt)
// MODE 5: bf16 out + per-block column sum/sumsq -> psum/psq[by][1024]  (y)
// MODE 6: merged projections, 3-way epilogue by n-block:
//         which=0 -> Qp (bf16, row-scale gamma^s)
//         which=1 -> Kt (bf16, transposed, scale gamma^-s)
//         which=2 -> Vt (bf16, transposed)
// ---------------------------------------------------------------------------
template<int MODE>
__global__ __launch_bounds__(1024, 4)
void gemm_bf(const ushort* __restrict__ A0, const ushort* __restrict__ B0,
             void* __restrict__ C0, void* __restrict__ C1, void* __restrict__ C2,
             float* __restrict__ psum, float* __restrict__ psq,
             long sA, long sB, long sBm, long sC, float coef)
{
    __shared__ __align__(16) char lds[131072];  // 2 bufs x (A 32K + B 32K)

    // ---- bijective XCD swizzle (all grids are multiples of 8 blocks) ----
    const int gx = gridDim.x, gy = gridDim.y;
    int lid   = blockIdx.x + gx * (blockIdx.y + gy * blockIdx.z);
    int total = gx * gy * gridDim.z;
    int swz   = (lid & 7) * (total >> 3) + (lid >> 3);
    int bx = swz % gx;
    int rest = swz / gx;
    int by = rest % gy;
    int bz = rest / gy;

    const int m0 = by * 256, n0 = bx * 256;
    const ushort* A  = A0 + (long)bz * sA;
    const ushort* Bp = B0 + (long)bz * sB + (long)(m0 >> 10) * sBm;

    const int t = threadIdx.x;
    const int l = t & 63, w = t >> 6;     // 16 waves
    const int wr = w >> 2, wc = w & 3;    // wave grid 4M x 4N
    const int ln = l & 31;                // MFMA row/col lane
    const int kb = l >> 5;                // k half (0/1)
    const int lx = l & 7;                 // swizzle xor for frag reads

    // frag-read lane bases (byte offsets inside a buffer)
    const int aOff = (wr * 64 + ln) * 128;            // + mi*4096
    const int bOff = 32768 + (wc * 64 + ln) * 128;    // + nj*4096

    // ---- staging: thread t writes 16B at linear LDS t*16; source address
    //      pre-swizzled so phys slot s of row r holds chunk (s ^ (r&7)).
    //      1024 thr x 16B = 16KB per issue = 128 rows; 2 issues per matrix.
    const int rl   = t >> 3;                 // row within 128-row chunk
    const int slot = (t & 7) ^ (rl & 7);
    const ushort* gA = A  + (long)(m0 + rl) * 1024 + slot * 8;
    const ushort* gB = Bp + (long)(n0 + rl) * 1024 + slot * 8;
    char* lA = lds + t * 16;                 // + buf + h*16384
    char* lB = lds + 32768 + t * 16;

#define STA(h, k0, bo_) gload16(gA + (long)(h) * 131072 + (k0), lA + (bo_) + (h) * 16384)
#define STB(h, k0, bo_) gload16(gB + (long)(h) * 131072 + (k0), lB + (bo_) + (h) * 16384)

    f32x16 acc[2][2] = {};

    // ---- prologue: stage tile 0 into buf 0 ----
    STA(0, 0, 0); STA(1, 0, 0); STB(0, 0, 0); STB(1, 0, 0);
    SCHED0;
    asm volatile("s_waitcnt vmcnt(0)" ::: "memory");
    SCHED0;
    __builtin_amdgcn_s_barrier();
    SCHED0;

    for (int kt = 0; kt < 16; ++kt) {
        const int bo = (kt & 1) << 16;
        const int bn = bo ^ 65536;
        const int k1 = (kt + 1) << 6;
        const bool st = kt < 15;
        const char* base = lds + bo;

#pragma unroll
        for (int p = 0; p < 4; ++p) {
            const int sxp = ((p * 2 + kb) ^ lx) * 16;
            short8 a0 = *(const short8*)(base + aOff + 0 * 4096 + sxp);
            short8 a1 = *(const short8*)(base + aOff + 1 * 4096 + sxp);
            short8 b0 = *(const short8*)(base + bOff + 0 * 4096 + sxp);
            short8 b1 = *(const short8*)(base + bOff + 1 * 4096 + sxp);
            if (st) {
                if (p == 0) { STA(0, k1, bn); STA(1, k1, bn); }
                else if (p == 1) { STB(0, k1, bn); STB(1, k1, bn); }
            }
            __builtin_amdgcn_s_setprio(1);
            acc[0][0] = MFMA32(a0, b0, acc[0][0]);
            acc[0][1] = MFMA32(a0, b1, acc[0][1]);
            acc[1][0] = MFMA32(a1, b0, acc[1][0]);
            acc[1][1] = MFMA32(a1, b1, acc[1][1]);
            __builtin_amdgcn_s_setprio(0);
            SCHED0;
        }
        // tile boundary: own prefetch landed + all waves done reading bo
        asm volatile("s_waitcnt vmcnt(0)" ::: "memory");
        SCHED0;
        __builtin_amdgcn_s_barrier();
        SCHED0;
    }

    // C/D 32x32 layout: col = ln, row = (reg&3) + 8*(reg>>2) + 4*kb
    // ---------------- epilogues ----------------
    if constexpr (MODE == 4) {
        ushort* C = (ushort*)C0 + (long)bz * sC;
#pragma unroll
        for (int mi = 0; mi < 2; ++mi)
#pragma unroll
            for (int reg = 0; reg < 16; ++reg) {
                int row = m0 + wr * 64 + mi * 32 + (reg & 3) + 8 * (reg >> 2) + 4 * kb;
#pragma unroll
                for (int nj = 0; nj < 2; ++nj)
                    C[(long)row * 1024 + n0 + wc * 64 + nj * 32 + ln] =
                        f2b(acc[mi][nj][reg]);
            }
    } else if constexpr (MODE == 5) {
        // bf16 y out + per-block column sums/sumsq (fused GroupNorm stats)
        ushort* C = (ushort*)C0;
        float cs0 = 0.f, cq0 = 0.f, cs1 = 0.f, cq1 = 0.f;
#pragma unroll
        for (int mi = 0; mi < 2; ++mi)
#pragma unroll
            for (int reg = 0; reg < 16; ++reg) {
                float v0 = acc[mi][0][reg], v1 = acc[mi][1][reg];
                cs0 += v0; cq0 += v0 * v0;
                cs1 += v1; cq1 += v1 * v1;
                int row = m0 + wr * 64 + mi * 32 + (reg & 3) + 8 * (reg >> 2) + 4 * kb;
                C[(long)row * 1024 + n0 + wc * 64 + ln]      = f2b(v0);
                C[(long)row * 1024 + n0 + wc * 64 + 32 + ln] = f2b(v1);
            }
        float* S4 = (float*)lds;            // [256 cols][8]
        float* Q4 = (float*)(lds + 8192);
        {
            int c0i = wc * 64 + ln, c1i = wc * 64 + 32 + ln, idx = wr * 2 + kb;
            S4[c0i * 8 + idx] = cs0; S4[c1i * 8 + idx] = cs1;
            Q4[c0i * 8 + idx] = cq0; Q4[c1i * 8 + idx] = cq1;
        }
        __syncthreads();
        if (t < 256) {
            float s = 0.f, q = 0.f;
#pragma unroll
            for (int z = 0; z < 8; ++z) { s += S4[t * 8 + z]; q += Q4[t * 8 + z]; }
            psum[(long)by * 1024 + n0 + t] = s;
            psq [(long)by * 1024 + n0 + t] = q;
        }
    } else {
        // MODE 6: merged projections
        const int which = n0 >> 10;       // 0=Q, 1=K, 2=V
        const int nq = n0 & 1023;
        if (which == 0) {
            ushort* C = (ushort*)C0;
#pragma unroll
            for (int mi = 0; mi < 2; ++mi)
#pragma unroll
                for (int reg = 0; reg < 16; ++reg) {
                    int row = m0 + wr * 64 + mi * 32 + (reg & 3) + 8 * (reg >> 2) + 4 * kb;
                    float s = exp2f(coef * (float)(row & 1023));
#pragma unroll
                    for (int nj = 0; nj < 2; ++nj)
                        C[(long)row * 1024 + nq + wc * 64 + nj * 32 + ln] =
                            f2b(acc[mi][nj][reg] * s);
                }
        } else {
            // transposed store via LDS bounce (phys slot = rowgroup ^ (cn&31)),
            // packed ushort4 (8B) writes, coalesced ushort8 readout. out[b][d][s]
            ushort* Tl = (ushort*)lds;
            const int bb = m0 >> 10;          // batch index
            const int ms = m0 & 1023;         // s-offset within batch
            ushort* Ct = (ushort*)((which == 1) ? C1 : C2) + (long)bb * sC;
            const float cf = (which == 1) ? -coef : 0.0f;
            __syncthreads();
#pragma unroll
            for (int mi = 0; mi < 2; ++mi)
#pragma unroll
                for (int g = 0; g < 4; ++g) {
                    int rq = wr * 8 + mi * 4 + g;      // rm>>3
                    int rb = 8 * g + 4 * kb;           // row base within (mi, kb)
#pragma unroll
                    for (int nj = 0; nj < 2; ++nj) {
                        int cn = wc * 64 + nj * 32 + ln;
                        int p  = rq ^ (cn & 31);
                        ushort4_t u;
#pragma unroll
                        for (int e = 0; e < 4; ++e) {
                            int rm = wr * 64 + mi * 32 + rb + e;
                            float s = exp2f(cf * (float)(ms + rm));
                            u[e] = f2b(acc[mi][nj][g * 4 + e] * s);
                        }
                        *(ushort4_t*)&Tl[cn * 256 + p * 8 + 4 * kb] = u;
                    }
                }
            __syncthreads();
#pragma unroll
            for (int it = 0; it < 8; ++it) {
                int cn = (t >> 5) + it * 32;
                int ch = t & 31;
                int p  = ch ^ (cn & 31);
                ushort8 v = *(const ushort8*)&Tl[cn * 256 + p * 8];
                *(ushort8*)&Ct[(long)(nq + cn) * 1024 + ms + ch * 8] = v;
            }
        }
    }
#undef STA
#undef STB
}

// ---------------- prepass: fp32 -> bf16 convert ----------------
__global__ __launch_bounds__(256)
void conv_x_k(const float* __restrict__ x, ushort* __restrict__ xb)
{
    long i = ((long)blockIdx.x * 256 + threadIdx.x) * 8;
    float4 a = *(const float4*)&x[i];
    float4 b = *(const float4*)&x[i + 4];
    ushort8 v;
    v[0] = f2b(a.x); v[1] = f2b(a.y); v[2] = f2b(a.z); v[3] = f2b(a.w);
    v[4] = f2b(b.x); v[5] = f2b(b.y); v[6] = f2b(b.z); v[7] = f2b(b.w);
    *(ushort8*)&xb[i] = v;
}

// ---------------- prepass: weight transpose + convert ----------------
__global__ __launch_bounds__(256)
void wt_k(const float* __restrict__ W, ushort* __restrict__ Wt)
{
    __shared__ float Tl[32][33];
    int tx = threadIdx.x & 31, ty = threadIdx.x >> 5;
    int c0 = blockIdx.x * 32, r0 = blockIdx.y * 32;
#pragma unroll
    for (int i = 0; i < 4; i++)
        Tl[ty + 8 * i][tx] = W[(long)(r0 + ty + 8 * i) * 1024 + c0 + tx];
    __syncthreads();
#pragma unroll
    for (int i = 0; i < 4; i++)
        Wt[(long)(c0 + ty + 8 * i) * 1024 + r0 + tx] = f2b(Tl[tx][ty + 8 * i]);
}

// ---------------- GroupNorm: finalize stats -> fused scale/bias ----------------
__global__ __launch_bounds__(256)
void stats2(const float* __restrict__ psum, const float* __restrict__ psq,
            const float* __restrict__ gsc, const float* __restrict__ gbt,
            float* __restrict__ fs, float* __restrict__ bias)
{
    int d = blockIdx.x * 256 + threadIdx.x;
    int b = blockIdx.y;
    float s = 0.f, q = 0.f;
#pragma unroll
    for (int z = 0; z < 4; z++) {
        long o = ((long)(b * 4 + z) << 10) + d;
        s += psum[o];
        q += psq[o];
    }
    float mean = s * (1.0f / SN_);
    float var  = q * (1.0f / SN_) - mean * mean;
    var = fmaxf(var, 0.0f);
    float rstd = rsqrtf(var + EPS_);
    float f = rstd * gsc[d];
    fs[(long)b * DN_ + d]   = f;
    bias[(long)b * DN_ + d] = gbt[d] - mean * f;
}

// ---------------- normalize: bf16 y -> fp32 out ----------------
__global__ __launch_bounds__(256)
void norm_k(const ushort* __restrict__ yb, const float* __restrict__ fs,
            const float* __restrict__ bias, float* __restrict__ out)
{
    long i = ((long)blockIdx.x * 256 + threadIdx.x) * 8;
    int d = (int)(i & (DN_ - 1));
    int b = (int)(i >> 20);
    ushort8 v = *(const ushort8*)&yb[i];
    long o = (long)b * DN_ + d;
    float4 f0 = *(const float4*)&fs[o];
    float4 f1 = *(const float4*)&fs[o + 4];
    float4 b0 = *(const float4*)&bias[o];
    float4 b1 = *(const float4*)&bias[o + 4];
    float4 o0, o1;
    o0.x = __uint_as_float((unsigned)v[0] << 16) * f0.x + b0.x;
    o0.y = __uint_as_float((unsigned)v[1] << 16) * f0.y + b0.y;
    o0.z = __uint_as_float((unsigned)v[2] << 16) * f0.z + b0.z;
    o0.w = __uint_as_float((unsigned)v[3] << 16) * f0.w + b0.w;
    o1.x = __uint_as_float((unsigned)v[4] << 16) * f1.x + b1.x;
    o1.y = __uint_as_float((unsigned)v[5] << 16) * f1.y + b1.y;
    o1.z = __uint_as_float((unsigned)v[6] << 16) * f1.z + b1.z;
    o1.w = __uint_as_float((unsigned)v[7] << 16) * f1.w + b1.w;
    *(float4*)&out[i]     = o0;
    *(float4*)&out[i + 4] = o1;
}

extern "C" void kernel_launch(void* const* d_in, const int* in_sizes, int n_in,
                              void* d_out, int out_size, void* d_ws, size_t ws_size,
                              hipStream_t stream)
{
    const float* x   = (const float*)d_in[0];
    const float* Wq  = (const float*)d_in[1];
    const float* Wk  = (const float*)d_in[2];
    const float* Wv  = (const float*)d_in[3];
    const float* gsc = (const float*)d_in[4];
    const float* gbt = (const float*)d_in[5];
    float* out = (float*)d_out;

    const long SD = (long)SN_ * DN_;
    const long DD = (long)DN_ * DN_;
    const size_t MB32 = (size_t)SD * BATCH_ * sizeof(ushort);  // 32 MiB

    char* ws = (char*)d_ws;
    ushort* xb  = (ushort*)(ws);            // x bf16; reused as yb after projs
    ushort* Qp  = (ushort*)(ws + 1 * MB32);
    ushort* Kt  = (ushort*)(ws + 2 * MB32);
    ushort* Vt  = (ushort*)(ws + 3 * MB32);
    ushort* Mt  = (ushort*)(ws + 4 * MB32);
    ushort* Wct = (ushort*)(ws + 5 * MB32);                       // [3072][1024] bf16
    float*  psum = (float*)(ws + 5 * MB32 + (6u << 20));          // [64][1024]
    float*  psq  = (float*)(ws + 5 * MB32 + (6u << 20) + (1u << 18));
    float*  fs   = (float*)(ws + 5 * MB32 + (6u << 20) + (2u << 18));
    float*  bias = (float*)(ws + 5 * MB32 + (6u << 20) + (2u << 18) + (1u << 16));
    ushort* yb  = xb;

    const float lgf = (float)log2(0.96875);  // log2(gamma)

    dim3 blk1k(1024);
    dim3 blk(256);
    dim3 gproj(12, 64);     // N=3072/256, M=16384/256  (768 blocks)
    dim3 gmt(4, 4, 16);     // per-batch 1024x1024      (256 blocks)
    dim3 gy(4, 64);         // N=1024/256, M=16384/256  (256 blocks)

    // prepass
    conv_x_k<<<dim3(8192), blk, 0, stream>>>(x, xb);
    wt_k<<<dim3(32, 32), blk, 0, stream>>>(Wq, Wct);
    wt_k<<<dim3(32, 32), blk, 0, stream>>>(Wk, Wct + 1024 * 1024);
    wt_k<<<dim3(32, 32), blk, 0, stream>>>(Wv, Wct + 2 * 1024 * 1024);

    // merged projections: Q' (scale gamma^s), K't (transp, gamma^-s), V't (transp)
    gemm_bf<6><<<gproj, blk1k, 0, stream>>>(xb, Wct, Qp, Kt, Vt,
                                            nullptr, nullptr,
                                            0, 0, 0, SD, lgf);
    // Mt = V't x Kt(B^T) = M^T   [B][D][D] bf16
    gemm_bf<4><<<gmt, blk1k, 0, stream>>>(Vt, Kt, Mt, nullptr, nullptr,
                                          nullptr, nullptr,
                                          SD, SD, 0, DD, 0.0f);
    // y = Q' x Mt(B^T per batch) -> bf16 yb + fused column stats
    gemm_bf<5><<<gy, blk1k, 0, stream>>>(Qp, Mt, yb, nullptr, nullptr,
                                         psum, psq,
                                         0, 0, DD, 0, 0.0f);

    // GroupNorm finalize + apply
    stats2<<<dim3(4, 16), blk, 0, stream>>>(psum, psq, gsc, gbt, fs, bias);
    norm_k<<<dim3(8192), blk, 0, stream>>>(yb, fs, bias, out);
}